// Round 1
// baseline (2371.935 us; speedup 1.0000x reference)
//
#include <hip/hip_runtime.h>
#include <stdint.h>

typedef unsigned int u32;
typedef unsigned long long u64;
typedef unsigned short u16;

#define S_ 1024
#define D_ 64
#define NH_ 64
#define BINS_ 16384
#define BSHIFT_ 18
#define TOPK_ 4096u
#define LCAP_ 16384
#define RCAP_ 48
#define EPS_ 1e-5f
#define LOGN_ 13.862943611198906f   // log(1024*1024)

__device__ __forceinline__ u32 mono_key(float s){
  u32 u = __float_as_uint(s);
  return (u >> 31) ? ~u : (u | 0x80000000u);   // ascending monotone map
}
__device__ __forceinline__ u16 f2b(float f){
  u32 u = __float_as_uint(f);
  return (u16)((u + 0x7FFFu + ((u >> 16) & 1u)) >> 16);   // f32 -> bf16 RNE
}
__device__ __forceinline__ float b2f(u16 b){
  return __uint_as_float(((u32)b) << 16);
}

// ---------------- K1: inverse row norms 1/(||x||+eps) ----------------
__global__ __launch_bounds__(256) void k1_norms(const float* __restrict__ Q,
    const float* __restrict__ K, float* __restrict__ qinv, float* __restrict__ kinv){
  int gw = (int)((blockIdx.x * blockDim.x + threadIdx.x) >> 6);
  int lane = threadIdx.x & 63;
  if (gw >= 2 * NH_ * S_) return;
  const float* src; float* dst; int row;
  if (gw < NH_ * S_){ src = Q; dst = qinv; row = gw; }
  else               { src = K; dst = kinv; row = gw - NH_ * S_; }
  float x = src[(u64)row * D_ + lane];
  float ss = x * x;
  #pragma unroll
  for (int m = 32; m; m >>= 1) ss += __shfl_xor(ss, m, 64);
  if (lane == 0) dst[row] = 1.0f / (sqrtf(ss) + EPS_);
}

// ---------------- K2: score recompute + per-head histogram over top-14 key bits ----------------
// grid: 64 heads * 8 chunks of 128 q-rows; block 256
__global__ __launch_bounds__(256) void k2_hist(
    const float* __restrict__ Q, const float* __restrict__ K,
    const float* __restrict__ qinv, const float* __restrict__ kinv,
    u32* __restrict__ Hist)
{
  __shared__ u32 hist[BINS_];        // 64KB
  __shared__ float kt[64 * 64];      // 16KB, float4-rotated layout
  const int t = threadIdx.x;
  const int h  = blockIdx.x >> 3;
  const int qc = blockIdx.x & 7;
  const float* Qh = Q + (u64)h * S_ * D_;
  const float* Kh = K + (u64)h * S_ * D_;
  for (int i = t; i < BINS_; i += 256) hist[i] = 0u;
  const int aq = t >> 4, ak = t & 15;

  for (int kt0 = 0; kt0 < 16; ++kt0){
    const int k0 = kt0 * 64;
    __syncthreads();   // protect kt from previous iteration readers (and hist init, 1st iter)
    for (int i = t; i < 1024; i += 256){
      int kr = i >> 4, c = i & 15;
      float4 v = *(const float4*)(Kh + (u64)(k0 + kr) * D_ + c * 4);
      *(float4*)(kt + kr * 64 + ((c + (kr >> 2)) & 15) * 4) = v;
    }
    __syncthreads();
    for (int qt = 0; qt < 2; ++qt){
      const int qb = qc * 128 + qt * 64 + aq * 4;
      float sa[4][4] = {};
      for (int d4 = 0; d4 < 16; ++d4){
        float4 qv[4], kv[4];
        #pragma unroll
        for (int i = 0; i < 4; ++i)
          qv[i] = *(const float4*)(Qh + (u64)(qb + i) * D_ + d4 * 4);
        #pragma unroll
        for (int j = 0; j < 4; ++j)
          kv[j] = *(const float4*)(kt + (ak * 4 + j) * 64 + ((d4 + ak) & 15) * 4);
        #pragma unroll
        for (int i = 0; i < 4; ++i)
          #pragma unroll
          for (int j = 0; j < 4; ++j){
            sa[i][j] = fmaf(qv[i].x, kv[j].x, sa[i][j]);
            sa[i][j] = fmaf(qv[i].y, kv[j].y, sa[i][j]);
            sa[i][j] = fmaf(qv[i].z, kv[j].z, sa[i][j]);
            sa[i][j] = fmaf(qv[i].w, kv[j].w, sa[i][j]);
          }
      }
      #pragma unroll
      for (int i = 0; i < 4; ++i){
        float qi = qinv[h * S_ + qb + i];
        #pragma unroll
        for (int j = 0; j < 4; ++j){
          float s = sa[i][j] * qi * kinv[h * S_ + k0 + ak * 4 + j];
          u32 bin = mono_key(s) >> BSHIFT_;
          atomicAdd(&hist[bin], 1u);
        }
      }
    }
  }
  __syncthreads();
  for (int i = t; i < BINS_; i += 256){
    u32 c = hist[i];
    if (c) atomicAdd(&Hist[(u64)h * BINS_ + i], c);
  }
}

// ---------------- K3: per-head suffix scan -> midpoint-weight table (bf16) + top-bin threshold ----------------
// grid: 64 blocks of 256
__global__ __launch_bounds__(256) void k3_scan(
    const u32* __restrict__ Hist, u16* __restrict__ Wb, u32* __restrict__ bstar)
{
  __shared__ u32 csum[256];
  const int h = blockIdx.x, t = threadIdx.x;
  const u32* Hh = Hist + (u64)h * BINS_;
  u32 local = 0;
  for (int i = 0; i < 64; ++i) local += Hh[t * 64 + i];
  csum[t] = local;
  __syncthreads();
  for (int off = 1; off < 256; off <<= 1){
    u32 v = (t + off < 256) ? csum[t + off] : 0u;
    __syncthreads();
    csum[t] += v;
    __syncthreads();
  }
  u32 g = csum[t] - local;     // elements in chunks strictly above
  u32 bmin = 0xFFFFFFFFu;
  for (int i = 63; i >= 0; --i){
    int bin = t * 64 + i;
    u32 c = Hh[bin];
    float wmid = LOGN_ - logf((float)g + 0.5f * ((float)c + 1.0f));
    Wb[(u64)h * BINS_ + bin] = f2b(wmid);
    if (g < TOPK_) bmin = (u32)bin;
    g += c;
  }
  if (bmin != 0xFFFFFFFFu) atomicMin(&bstar[h], bmin);
}

// ---------------- K4: fused score recompute + weight gather + W@V + Z + top-element collect ----------------
// grid: 64 heads * 16 q-tiles(64 rows); block 256
__global__ __launch_bounds__(256) void k4_main(
    const float* __restrict__ Q, const float* __restrict__ K, const float* __restrict__ V,
    const float* __restrict__ qinv, const float* __restrict__ kinv,
    const u16* __restrict__ Wb, const u32* __restrict__ bstar,
    u32* __restrict__ listCount, u64* __restrict__ list,
    float* __restrict__ Zrow, float* __restrict__ out)
{
  __shared__ u16 wbl[BINS_];       // 32KB
  __shared__ float wt[64 * 64];    // 16KB (xor-swizzled on k index)
  __shared__ float kt[64 * 64];    // 16KB
  __shared__ float qts[64 * 64];   // 16KB
  const int t = threadIdx.x;
  const int h  = blockIdx.x >> 4;
  const int q0 = (blockIdx.x & 15) * 64;
  const float* Qh = Q + (u64)h * S_ * D_;
  const float* Kh = K + (u64)h * S_ * D_;
  const float* Vh = V + (u64)h * S_ * D_;
  for (int i = t; i < BINS_; i += 256) wbl[i] = Wb[(u64)h * BINS_ + i];
  for (int i = t; i < 1024; i += 256){
    int qr = i >> 4, c = i & 15;
    float4 v = *(const float4*)(Qh + (u64)(q0 + qr) * D_ + c * 4);
    *(float4*)(qts + qr * 64 + ((c + (qr >> 2)) & 15) * 4) = v;
  }
  const u32 bst = bstar[h];
  const int aq = t >> 4, ak = t & 15;
  float qiv[4];
  #pragma unroll
  for (int i = 0; i < 4; ++i) qiv[i] = qinv[h * S_ + q0 + aq * 4 + i];
  float zacc[4] = {0, 0, 0, 0};
  float acc[4][4] = {};

  for (int kt0 = 0; kt0 < 16; ++kt0){
    const int k0 = kt0 * 64;
    for (int i = t; i < 1024; i += 256){
      int kr = i >> 4, c = i & 15;
      float4 v = *(const float4*)(Kh + (u64)(k0 + kr) * D_ + c * 4);
      *(float4*)(kt + kr * 64 + ((c + (kr >> 2)) & 15) * 4) = v;
    }
    __syncthreads();   // staging done (also covers wbl/qts on 1st iter)

    // phase A: 4q x 4k scores per thread
    float sa[4][4] = {};
    for (int d4 = 0; d4 < 16; ++d4){
      float4 qv[4], kv[4];
      #pragma unroll
      for (int i = 0; i < 4; ++i)
        qv[i] = *(const float4*)(qts + (aq * 4 + i) * 64 + ((d4 + aq) & 15) * 4);
      #pragma unroll
      for (int j = 0; j < 4; ++j)
        kv[j] = *(const float4*)(kt + (ak * 4 + j) * 64 + ((d4 + ak) & 15) * 4);
      #pragma unroll
      for (int i = 0; i < 4; ++i)
        #pragma unroll
        for (int j = 0; j < 4; ++j){
          sa[i][j] = fmaf(qv[i].x, kv[j].x, sa[i][j]);
          sa[i][j] = fmaf(qv[i].y, kv[j].y, sa[i][j]);
          sa[i][j] = fmaf(qv[i].z, kv[j].z, sa[i][j]);
          sa[i][j] = fmaf(qv[i].w, kv[j].w, sa[i][j]);
        }
    }
    #pragma unroll
    for (int i = 0; i < 4; ++i){
      int qrow = aq * 4 + i;
      #pragma unroll
      for (int j = 0; j < 4; ++j){
        int kl = ak * 4 + j;
        float s = sa[i][j] * qiv[i] * kinv[h * S_ + k0 + kl];
        u32 key = mono_key(s);
        u32 bin = key >> BSHIFT_;
        float w = b2f(wbl[bin]);
        wt[qrow * 64 + (kl ^ (qrow & 15))] = w;
        zacc[i] += w;
        if (bin >= bst){
          u32 pos = (u32)((q0 + qrow) * S_ + (k0 + kl));
          u32 idx = atomicAdd(&listCount[h], 1u);
          if (idx < LCAP_)
            list[(u64)h * LCAP_ + idx] = ((u64)key << 32) | (u64)(0xFFFFFFFFu - pos);
        }
      }
    }
    __syncthreads();   // wt ready

    // phase B: out[64q x 64d] += wt * V-tile  (thread = (qq=aq) rows x (dd=ak) cols)
    #pragma unroll 4
    for (int kk = 0; kk < 64; ++kk){
      float4 vv = *(const float4*)(Vh + (u64)(k0 + kk) * D_ + ak * 4);
      float wq[4];
      #pragma unroll
      for (int i = 0; i < 4; ++i){
        int qrow = aq * 4 + i;
        wq[i] = wt[qrow * 64 + (kk ^ (qrow & 15))];
      }
      #pragma unroll
      for (int i = 0; i < 4; ++i){
        acc[i][0] = fmaf(wq[i], vv.x, acc[i][0]);
        acc[i][1] = fmaf(wq[i], vv.y, acc[i][1]);
        acc[i][2] = fmaf(wq[i], vv.z, acc[i][2]);
        acc[i][3] = fmaf(wq[i], vv.w, acc[i][3]);
      }
    }
    __syncthreads();   // done with wt/kt before next staging
  }

  #pragma unroll
  for (int i = 0; i < 4; ++i){
    int q = q0 + aq * 4 + i;
    *(float4*)(out + ((u64)h * S_ + q) * D_ + ak * 4) =
        make_float4(acc[i][0], acc[i][1], acc[i][2], acc[i][3]);
  }
  #pragma unroll
  for (int m = 1; m < 16; m <<= 1){
    #pragma unroll
    for (int i = 0; i < 4; ++i) zacc[i] += __shfl_xor(zacc[i], m, 64);
  }
  if (ak == 0){
    #pragma unroll
    for (int i = 0; i < 4; ++i) Zrow[h * S_ + q0 + aq * 4 + i] = zacc[i];
  }
}

// ---------------- K5: exact ranks for top list, emit per-row corrections ----------------
// grid: 64 heads * 8 slices; block 256
__global__ __launch_bounds__(256) void k5_exact(
    const u64* __restrict__ list, const u32* __restrict__ listCount,
    const u16* __restrict__ Wb,
    u32* __restrict__ rowcnt, u32* __restrict__ rowk, float* __restrict__ rowdw)
{
  __shared__ u64 codes[8192];     // 64KB
  const int h = blockIdx.x >> 3, sl = blockIdx.x & 7, t = threadIdx.x;
  u32 T = listCount[h]; if (T > LCAP_) T = LCAP_;
  const u64* lh = list + (u64)h * LCAP_;
  u32 e0 = (T * (u32)sl) / 8u, e1 = (T * (u32)(sl + 1)) / 8u;

  u64 mc[8]; u32 rr[8]; bool val[8];
  #pragma unroll
  for (int i = 0; i < 8; ++i){
    u32 e = e0 + (u32)t + (u32)i * 256u;
    val[i] = (e < e1);
    mc[i] = val[i] ? lh[e] : 0xFFFFFFFFFFFFFFFFull;
    rr[i] = 0;
  }
  for (u32 c0 = 0; c0 < T; c0 += 8192u){
    u32 cn = T - c0; if (cn > 8192u) cn = 8192u;
    __syncthreads();
    for (u32 i = t; i < cn; i += 256) codes[i] = lh[c0 + i];
    __syncthreads();
    for (u32 j = 0; j < cn; ++j){
      u64 cj = codes[j];
      #pragma unroll
      for (int i = 0; i < 8; ++i) rr[i] += (cj > mc[i]) ? 1u : 0u;
    }
  }
  #pragma unroll
  for (int i = 0; i < 8; ++i){
    if (!val[i]) continue;
    float wex = LOGN_ - logf((float)(rr[i] + 1u));
    u32 key = (u32)(mc[i] >> 32);
    float dw = wex - b2f(Wb[(u64)h * BINS_ + (key >> BSHIFT_)]);
    u32 pos = 0xFFFFFFFFu - (u32)(mc[i] & 0xFFFFFFFFull);
    u32 q = pos >> 10, k = pos & 1023u;
    u32 idx = atomicAdd(&rowcnt[h * S_ + q], 1u);
    if (idx < RCAP_){
      rowk [((u64)(h * S_ + q)) * RCAP_ + idx] = k;
      rowdw[((u64)(h * S_ + q)) * RCAP_ + idx] = dw;
    }
  }
}

// ---------------- K7: apply corrections + normalize rows ----------------
__global__ __launch_bounds__(256) void k7_fix(
    const float* __restrict__ V, const u32* __restrict__ rowcnt,
    const u32* __restrict__ rowk, const float* __restrict__ rowdw,
    const float* __restrict__ Zrow, float* __restrict__ out)
{
  int gw = (int)((blockIdx.x * blockDim.x + threadIdx.x) >> 6);
  int lane = threadIdx.x & 63;
  if (gw >= NH_ * S_) return;
  int h = gw >> 10;
  float v = out[(u64)gw * D_ + lane];
  float z = Zrow[gw];
  u32 c = rowcnt[gw]; if (c > RCAP_) c = RCAP_;
  const float* Vh = V + (u64)h * S_ * D_;
  for (u32 j = 0; j < c; ++j){
    u32 k  = rowk [(u64)gw * RCAP_ + j];
    float dw = rowdw[(u64)gw * RCAP_ + j];
    v = fmaf(dw, Vh[(u64)k * D_ + lane], v);
    z += dw;
  }
  out[(u64)gw * D_ + lane] = v / z;
}

extern "C" void kernel_launch(void* const* d_in, const int* in_sizes, int n_in,
                              void* d_out, int out_size, void* d_ws, size_t ws_size,
                              hipStream_t stream)
{
  (void)in_sizes; (void)n_in; (void)out_size;
  const float* Q = (const float*)d_in[0];
  const float* K = (const float*)d_in[1];
  const float* V = (const float*)d_in[2];
  float* out = (float*)d_out;

  uint8_t* w = (uint8_t*)d_ws;
  size_t off = 0;
  auto alloc = [&](size_t bytes) -> void* {
    void* p = w + off;
    off += (bytes + 255) & ~(size_t)255;
    return p;
  };
  float* qinv     = (float*)alloc((size_t)NH_ * S_ * 4);
  float* kinv     = (float*)alloc((size_t)NH_ * S_ * 4);
  u32*   Hist     = (u32*)  alloc((size_t)NH_ * BINS_ * 4);
  u16*   Wb       = (u16*)  alloc((size_t)NH_ * BINS_ * 2);
  u32*   bstar    = (u32*)  alloc((size_t)NH_ * 4);
  u32*   listCnt  = (u32*)  alloc((size_t)NH_ * 4);
  u64*   list     = (u64*)  alloc((size_t)NH_ * LCAP_ * 8);
  float* Zrow     = (float*)alloc((size_t)NH_ * S_ * 4);
  u32*   rowcnt   = (u32*)  alloc((size_t)NH_ * S_ * 4);
  u32*   rowk     = (u32*)  alloc((size_t)NH_ * S_ * RCAP_ * 4);
  float* rowdw    = (float*)alloc((size_t)NH_ * S_ * RCAP_ * 4);
  if (off > ws_size) return;   // ws too small: bail (will fail validation visibly)

  hipMemsetAsync(Hist,    0,    (size_t)NH_ * BINS_ * 4, stream);
  hipMemsetAsync(bstar,   0xFF, (size_t)NH_ * 4,         stream);
  hipMemsetAsync(listCnt, 0,    (size_t)NH_ * 4,         stream);
  hipMemsetAsync(rowcnt,  0,    (size_t)NH_ * S_ * 4,    stream);

  k1_norms<<<dim3(32768), dim3(256), 0, stream>>>(Q, K, qinv, kinv);
  k2_hist <<<dim3(512),   dim3(256), 0, stream>>>(Q, K, qinv, kinv, Hist);
  k3_scan <<<dim3(64),    dim3(256), 0, stream>>>(Hist, Wb, bstar);
  k4_main <<<dim3(1024),  dim3(256), 0, stream>>>(Q, K, V, qinv, kinv, Wb, bstar,
                                                  listCnt, list, Zrow, out);
  k5_exact<<<dim3(512),   dim3(256), 0, stream>>>(list, listCnt, Wb, rowcnt, rowk, rowdw);
  k7_fix  <<<dim3(16384), dim3(256), 0, stream>>>(V, rowcnt, rowk, rowdw, Zrow, out);
}

// Round 2
// 1867.392 us; speedup vs baseline: 1.2702x; 1.2702x over previous
//
#include <hip/hip_runtime.h>
#include <stdint.h>

typedef unsigned int u32;
typedef unsigned long long u64;
typedef unsigned short u16;
typedef __attribute__((ext_vector_type(8))) short bf16x8;
typedef __attribute__((ext_vector_type(4))) float f32x4;

#define S_ 1024
#define D_ 64
#define NH_ 64
#define BINS_ 16384
#define BSHIFT_ 18
#define TOPK_ 4096u
#define SAMP_ 4u
#define LCAP_ 16384
#define RCAP_ 48
#define EPS_ 1e-5f
#define LOGN_ 13.862943611198906f   // log(1024*1024)

__device__ __forceinline__ u32 mono_key(float s){
  u32 u = __float_as_uint(s);
  return (u >> 31) ? ~u : (u | 0x80000000u);   // ascending monotone map
}
__device__ __forceinline__ u16 f2b(float f){
  u32 u = __float_as_uint(f);
  return (u16)((u + 0x7FFFu + ((u >> 16) & 1u)) >> 16);   // f32 -> bf16 RNE
}
__device__ __forceinline__ float b2f(u16 b){
  return __uint_as_float(((u32)b) << 16);
}

// ---------------- K1: inverse norms + normalized bf16 Q,K ----------------
__global__ __launch_bounds__(256) void k1_norm(const float* __restrict__ Q,
    const float* __restrict__ K, float* __restrict__ qinv, float* __restrict__ kinv,
    u16* __restrict__ Qn, u16* __restrict__ Kn){
  int gw = (int)((blockIdx.x * blockDim.x + threadIdx.x) >> 6);
  int d = threadIdx.x & 63;
  if (gw >= 2 * NH_ * S_) return;
  const float* src; float* dst; u16* bdst; int row;
  if (gw < NH_ * S_){ src = Q; dst = qinv; bdst = Qn; row = gw; }
  else               { src = K; dst = kinv; bdst = Kn; row = gw - NH_ * S_; }
  float x = src[(u64)row * D_ + d];
  float ss = x * x;
  #pragma unroll
  for (int m = 32; m; m >>= 1) ss += __shfl_xor(ss, m, 64);
  float inv = 1.0f / (sqrtf(ss) + EPS_);
  if (d == 0) dst[row] = inv;
  bdst[(u64)row * D_ + d] = f2b(x * inv);
}

// ---------------- K1b: V -> VT (bf16, [h][d][k]) via LDS transpose ----------------
__global__ __launch_bounds__(256) void k1b_vt(const float* __restrict__ V,
                                             u16* __restrict__ VT){
  __shared__ u16 tr[64 * 65];
  const int t = threadIdx.x;
  const int h = blockIdx.x >> 4, k0 = (blockIdx.x & 15) * 64;
  for (int idx = t; idx < 4096; idx += 256){
    int r = idx >> 6, d = idx & 63;
    tr[d * 65 + r] = f2b(V[((u64)(h * S_ + k0 + r)) * D_ + d]);
  }
  __syncthreads();
  for (int idx = t; idx < 4096; idx += 256){
    int dr = idx >> 6, c = idx & 63;
    VT[((u64)(h * D_ + dr)) * S_ + k0 + c] = tr[dr * 65 + c];
  }
}

// ---------------- K2: sampled histogram via MFMA (1 block per head) ----------------
__global__ __launch_bounds__(512) void k2_hist(const u16* __restrict__ Qn,
    const u16* __restrict__ Kn, u32* __restrict__ Hist){
  __shared__ u32 hist[BINS_];                          // 64KB
  __shared__ __attribute__((aligned(16))) u16 kt2[64 * 64]; // 8KB
  const int t = threadIdx.x, h = blockIdx.x;
  const int w = t >> 6, l = t & 63, lr = l & 15, lg = l >> 4;
  for (int i = t; i < BINS_; i += 512) hist[i] = 0u;
  for (int st = 0; st < 4; ++st){
    const int k0 = (st * 4 + 1) * 64;   // sampled k-tiles {1,5,9,13}
    __syncthreads();
    { int srow = t >> 3, sslot = t & 7;
      *(uint4*)(kt2 + srow * 64 + ((sslot ^ (srow & 7)) * 8)) =
        *(const uint4*)(Kn + ((u64)(h * S_ + k0 + srow)) * D_ + sslot * 8);
    }
    __syncthreads();
    for (int qc = 0; qc < 8; ++qc){
      const u16* qrow = Qn + ((u64)(h * S_ + qc * 128 + w * 16 + lr)) * D_;
      bf16x8 qa0 = *(const bf16x8*)(qrow + lg * 8);
      bf16x8 qa1 = *(const bf16x8*)(qrow + lg * 8 + 32);
      #pragma unroll
      for (int j = 0; j < 4; ++j){
        int krow = j * 16 + lr, sw = krow & 7;
        bf16x8 kb0 = *(const bf16x8*)(kt2 + krow * 64 + ((lg ^ sw) * 8));
        bf16x8 kb1 = *(const bf16x8*)(kt2 + krow * 64 + (((lg + 4) ^ sw) * 8));
        f32x4 sa = {0.f, 0.f, 0.f, 0.f};
        sa = __builtin_amdgcn_mfma_f32_16x16x32_bf16(qa0, kb0, sa, 0, 0, 0);
        sa = __builtin_amdgcn_mfma_f32_16x16x32_bf16(qa1, kb1, sa, 0, 0, 0);
        #pragma unroll
        for (int r = 0; r < 4; ++r)
          atomicAdd(&hist[mono_key(sa[r]) >> BSHIFT_], 1u);
      }
    }
  }
  __syncthreads();
  for (int i = t; i < BINS_; i += 512) Hist[(u64)h * BINS_ + i] = hist[i];
}

// ---------------- K3: suffix scan (sampled counts x SAMP) -> weight table + bstar ----------------
__global__ __launch_bounds__(256) void k3_scan(
    const u32* __restrict__ Hist, u16* __restrict__ Wb, u32* __restrict__ bstar)
{
  __shared__ u32 csum[256];
  const int h = blockIdx.x, t = threadIdx.x;
  const u32* Hh = Hist + (u64)h * BINS_;
  u32 local = 0;
  for (int i = 0; i < 64; ++i) local += Hh[t * 64 + i];
  csum[t] = local;
  __syncthreads();
  for (int off = 1; off < 256; off <<= 1){
    u32 v = (t + off < 256) ? csum[t + off] : 0u;
    __syncthreads();
    csum[t] += v;
    __syncthreads();
  }
  u32 g = csum[t] - local;     // sampled count strictly above this thread's bins
  u32 bmin = 0xFFFFFFFFu;
  for (int i = 63; i >= 0; --i){
    int bin = t * 64 + i;
    u32 c = Hh[bin];
    float wmid = LOGN_ - logf((float)(SAMP_ * g) + 0.5f * ((float)(SAMP_ * c) + 1.0f));
    Wb[(u64)h * BINS_ + bin] = f2b(wmid);
    if (SAMP_ * g < TOPK_) bmin = (u32)bin;
    g += c;
  }
  if (bmin != 0xFFFFFFFFu) atomicMin(&bstar[h], bmin);
}

// ---------------- K4: MFMA QK^T -> bin/gather -> MFMA W@V + Z + top collect ----------------
// grid: 64 heads * 8 q-tiles(128 rows); block 512 (8 waves, 16 q-rows each)
__global__ __launch_bounds__(512) void k4_main(
    const u16* __restrict__ Qn, const u16* __restrict__ Kn, const u16* __restrict__ VT,
    const u16* __restrict__ Wb, const u32* __restrict__ bstar,
    u32* __restrict__ listCount, u64* __restrict__ list,
    float* __restrict__ Zrow, float* __restrict__ out)
{
  __shared__ u16 wbl[BINS_];                                 // 32KB
  __shared__ __attribute__((aligned(16))) u16 kt2[64 * 64];  // 8KB
  __shared__ __attribute__((aligned(16))) u16 vt2[64 * 64];  // 8KB
  __shared__ __attribute__((aligned(16))) u16 wt2[128 * 64]; // 16KB
  const int t = threadIdx.x;
  const int h = blockIdx.x >> 3;
  const int q0 = (blockIdx.x & 7) * 128;
  const int w = t >> 6, l = t & 63, lr = l & 15, lg = l >> 4;

  for (int i = t; i < BINS_; i += 512) wbl[i] = Wb[(u64)h * BINS_ + i];
  const u32 bst = bstar[h];

  const u16* qrow = Qn + ((u64)(h * S_ + q0 + w * 16 + lr)) * D_;
  bf16x8 qa0 = *(const bf16x8*)(qrow + lg * 8);
  bf16x8 qa1 = *(const bf16x8*)(qrow + lg * 8 + 32);

  f32x4 acc[4] = {{0,0,0,0},{0,0,0,0},{0,0,0,0},{0,0,0,0}};
  float zacc[4] = {0, 0, 0, 0};
  const int srow = t >> 3, sslot = t & 7;

  for (int kt0 = 0; kt0 < 16; ++kt0){
    const int k0 = kt0 * 64;
    __syncthreads();   // prev tile's reads of kt2/vt2/wt2 done (covers wbl init, 1st iter)
    *(uint4*)(kt2 + srow * 64 + ((sslot ^ (srow & 7)) * 8)) =
        *(const uint4*)(Kn + ((u64)(h * S_ + k0 + srow)) * D_ + sslot * 8);
    *(uint4*)(vt2 + srow * 64 + ((sslot ^ (srow & 7)) * 8)) =
        *(const uint4*)(VT + ((u64)(h * D_ + srow)) * S_ + k0 + sslot * 8);
    __syncthreads();   // staged

    // QK^T + per-element post
    #pragma unroll
    for (int j = 0; j < 4; ++j){
      int krow = j * 16 + lr, sw = krow & 7;
      bf16x8 kb0 = *(const bf16x8*)(kt2 + krow * 64 + ((lg ^ sw) * 8));
      bf16x8 kb1 = *(const bf16x8*)(kt2 + krow * 64 + (((lg + 4) ^ sw) * 8));
      f32x4 sa = {0.f, 0.f, 0.f, 0.f};
      sa = __builtin_amdgcn_mfma_f32_16x16x32_bf16(qa0, kb0, sa, 0, 0, 0);
      sa = __builtin_amdgcn_mfma_f32_16x16x32_bf16(qa1, kb1, sa, 0, 0, 0);
      #pragma unroll
      for (int r = 0; r < 4; ++r){
        u32 key = mono_key(sa[r]);
        u32 bin = key >> BSHIFT_;
        u16 wbits = wbl[bin];
        zacc[r] += b2f(wbits);
        int rw = 16 * w + lg * 4 + r;            // q-row within block tile
        int col = j * 16 + lr;
        int colp = (((col >> 3) ^ (rw & 7)) << 3) | (col & 7);
        wt2[rw * 64 + colp] = wbits;
        if (bin >= bst){
          u32 pos = ((u32)(q0 + rw) << 10) | (u32)(k0 + col);
          u32 idx = atomicAdd(&listCount[h], 1u);
          if (idx < LCAP_)
            list[(u64)h * LCAP_ + idx] = ((u64)wbits << 32) | (u64)pos;
        }
      }
    }
    __syncthreads();   // wt2 ready

    // W @ V-tile
    int ra = 16 * w + lr, swa = ra & 7;
    bf16x8 wa0 = *(const bf16x8*)(wt2 + ra * 64 + ((lg ^ swa) * 8));
    bf16x8 wa1 = *(const bf16x8*)(wt2 + ra * 64 + (((lg + 4) ^ swa) * 8));
    #pragma unroll
    for (int dt = 0; dt < 4; ++dt){
      int rv = dt * 16 + lr, swv = rv & 7;
      bf16x8 vb0 = *(const bf16x8*)(vt2 + rv * 64 + ((lg ^ swv) * 8));
      bf16x8 vb1 = *(const bf16x8*)(vt2 + rv * 64 + (((lg + 4) ^ swv) * 8));
      acc[dt] = __builtin_amdgcn_mfma_f32_16x16x32_bf16(wa0, vb0, acc[dt], 0, 0, 0);
      acc[dt] = __builtin_amdgcn_mfma_f32_16x16x32_bf16(wa1, vb1, acc[dt], 0, 0, 0);
    }
  }

  // write out (pre-normalization)
  #pragma unroll
  for (int r = 0; r < 4; ++r){
    int q = q0 + 16 * w + lg * 4 + r;
    #pragma unroll
    for (int dt = 0; dt < 4; ++dt)
      out[((u64)(h * S_ + q)) * D_ + dt * 16 + lr] = acc[dt][r];
  }
  // reduce z over the 16 lanes holding one row
  #pragma unroll
  for (int m = 1; m < 16; m <<= 1){
    #pragma unroll
    for (int r = 0; r < 4; ++r) zacc[r] += __shfl_xor(zacc[r], m, 64);
  }
  if (lr == 0){
    #pragma unroll
    for (int r = 0; r < 4; ++r)
      Zrow[h * S_ + q0 + 16 * w + lg * 4 + r] = zacc[r];
  }
}

// ---------------- K5a: exact f32 rescoring of the top list ----------------
__global__ __launch_bounds__(256) void k5a_score(
    const float* __restrict__ Q, const float* __restrict__ K,
    const float* __restrict__ qinv, const float* __restrict__ kinv,
    const u64* __restrict__ list, const u32* __restrict__ listCount,
    u64* __restrict__ keyex, u16* __restrict__ wbx)
{
  const int h = blockIdx.x >> 2, sub = blockIdx.x & 3, t = threadIdx.x;
  u32 T = listCount[h]; if (T > LCAP_) T = LCAP_;
  for (u32 e = (u32)(sub * 256 + t); e < T; e += 1024u){
    u64 ent = list[(u64)h * LCAP_ + e];
    u32 wbits = (u32)(ent >> 32);
    u32 pos = (u32)ent;
    u32 q = pos >> 10, k = pos & 1023u;
    const float4* qp = (const float4*)(Q + ((u64)(h * S_ + q)) * D_);
    const float4* kp = (const float4*)(K + ((u64)(h * S_ + k)) * D_);
    float s = 0.f;
    #pragma unroll
    for (int i = 0; i < 16; ++i){
      float4 a = qp[i], b = kp[i];
      s += a.x * b.x + a.y * b.y + a.z * b.z + a.w * b.w;
    }
    s *= qinv[h * S_ + q] * kinv[h * S_ + k];
    keyex[(u64)h * LCAP_ + e] = ((u64)mono_key(s) << 32) | (u64)(0xFFFFFFFFu - pos);
    wbx[(u64)h * LCAP_ + e] = (u16)wbits;
  }
}

// ---------------- K5b: exact pairwise ranks over list -> per-row corrections ----------------
__global__ __launch_bounds__(256) void k5b_rank(
    const u64* __restrict__ keyex, const u16* __restrict__ wbx,
    const u32* __restrict__ listCount,
    u32* __restrict__ rowcnt, u32* __restrict__ rowk, float* __restrict__ rowdw)
{
  __shared__ u64 codes[8192];     // 64KB
  const int h = blockIdx.x >> 3, sl = blockIdx.x & 7, t = threadIdx.x;
  u32 T = listCount[h]; if (T > LCAP_) T = LCAP_;
  const u64* lh = keyex + (u64)h * LCAP_;
  u32 e0 = (T * (u32)sl) / 8u, e1 = (T * (u32)(sl + 1)) / 8u;

  u64 mc[8]; u32 rr[8]; u16 wb[8]; bool val[8];
  #pragma unroll
  for (int i = 0; i < 8; ++i){
    u32 e = e0 + (u32)t + (u32)i * 256u;
    val[i] = (e < e1);
    mc[i] = val[i] ? lh[e] : 0xFFFFFFFFFFFFFFFFull;
    wb[i] = val[i] ? wbx[(u64)h * LCAP_ + e] : (u16)0;
    rr[i] = 0;
  }
  for (u32 c0 = 0; c0 < T; c0 += 8192u){
    u32 cn = T - c0; if (cn > 8192u) cn = 8192u;
    __syncthreads();
    for (u32 i = t; i < cn; i += 256) codes[i] = lh[c0 + i];
    __syncthreads();
    for (u32 j = 0; j < cn; ++j){
      u64 cj = codes[j];
      #pragma unroll
      for (int i = 0; i < 8; ++i) rr[i] += (cj > mc[i]) ? 1u : 0u;
    }
  }
  #pragma unroll
  for (int i = 0; i < 8; ++i){
    if (!val[i]) continue;
    float wex = LOGN_ - logf((float)(rr[i] + 1u));
    float dw = wex - b2f(wb[i]);
    u32 pos = 0xFFFFFFFFu - (u32)(mc[i] & 0xFFFFFFFFull);
    u32 q = pos >> 10, k = pos & 1023u;
    u32 idx = atomicAdd(&rowcnt[h * S_ + q], 1u);
    if (idx < RCAP_){
      rowk [((u64)(h * S_ + q)) * RCAP_ + idx] = k;
      rowdw[((u64)(h * S_ + q)) * RCAP_ + idx] = dw;
    }
  }
}

// ---------------- K7: apply corrections + normalize rows ----------------
__global__ __launch_bounds__(256) void k7_fix(
    const float* __restrict__ V, const u32* __restrict__ rowcnt,
    const u32* __restrict__ rowk, const float* __restrict__ rowdw,
    const float* __restrict__ Zrow, float* __restrict__ out)
{
  int gw = (int)((blockIdx.x * blockDim.x + threadIdx.x) >> 6);
  int lane = threadIdx.x & 63;
  if (gw >= NH_ * S_) return;
  int h = gw >> 10;
  float v = out[(u64)gw * D_ + lane];
  float z = Zrow[gw];
  u32 c = rowcnt[gw]; if (c > RCAP_) c = RCAP_;
  const float* Vh = V + (u64)h * S_ * D_;
  for (u32 j = 0; j < c; ++j){
    u32 k  = rowk [(u64)gw * RCAP_ + j];
    float dw = rowdw[(u64)gw * RCAP_ + j];
    v = fmaf(dw, Vh[(u64)k * D_ + lane], v);
    z += dw;
  }
  out[(u64)gw * D_ + lane] = v / z;
}

extern "C" void kernel_launch(void* const* d_in, const int* in_sizes, int n_in,
                              void* d_out, int out_size, void* d_ws, size_t ws_size,
                              hipStream_t stream)
{
  (void)in_sizes; (void)n_in; (void)out_size;
  const float* Q = (const float*)d_in[0];
  const float* K = (const float*)d_in[1];
  const float* V = (const float*)d_in[2];
  float* out = (float*)d_out;

  uint8_t* w = (uint8_t*)d_ws;
  size_t off = 0;
  auto alloc = [&](size_t bytes) -> void* {
    void* p = w + off;
    off += (bytes + 255) & ~(size_t)255;
    return p;
  };
  float* qinv   = (float*)alloc((size_t)NH_ * S_ * 4);
  float* kinv   = (float*)alloc((size_t)NH_ * S_ * 4);
  u16*   Qn     = (u16*)  alloc((size_t)NH_ * S_ * D_ * 2);
  u16*   Kn     = (u16*)  alloc((size_t)NH_ * S_ * D_ * 2);
  u16*   VT     = (u16*)  alloc((size_t)NH_ * S_ * D_ * 2);
  u32*   Hist   = (u32*)  alloc((size_t)NH_ * BINS_ * 4);
  u16*   Wb     = (u16*)  alloc((size_t)NH_ * BINS_ * 2);
  u32*   bstar  = (u32*)  alloc((size_t)NH_ * 4);
  u32*   listCnt= (u32*)  alloc((size_t)NH_ * 4);
  u64*   list   = (u64*)  alloc((size_t)NH_ * LCAP_ * 8);
  u64*   keyex  = (u64*)  alloc((size_t)NH_ * LCAP_ * 8);
  u16*   wbx    = (u16*)  alloc((size_t)NH_ * LCAP_ * 2);
  float* Zrow   = (float*)alloc((size_t)NH_ * S_ * 4);
  u32*   rowcnt = (u32*)  alloc((size_t)NH_ * S_ * 4);
  u32*   rowk   = (u32*)  alloc((size_t)NH_ * S_ * RCAP_ * 4);
  float* rowdw  = (float*)alloc((size_t)NH_ * S_ * RCAP_ * 4);
  if (off > ws_size) return;

  hipMemsetAsync(bstar,   0xFF, (size_t)NH_ * 4,      stream);
  hipMemsetAsync(listCnt, 0,    (size_t)NH_ * 4,      stream);
  hipMemsetAsync(rowcnt,  0,    (size_t)NH_ * S_ * 4, stream);

  k1_norm <<<dim3(32768), dim3(256), 0, stream>>>(Q, K, qinv, kinv, Qn, Kn);
  k1b_vt  <<<dim3(1024),  dim3(256), 0, stream>>>(V, VT);
  k2_hist <<<dim3(64),    dim3(512), 0, stream>>>(Qn, Kn, Hist);
  k3_scan <<<dim3(64),    dim3(256), 0, stream>>>(Hist, Wb, bstar);
  k4_main <<<dim3(512),   dim3(512), 0, stream>>>(Qn, Kn, VT, Wb, bstar,
                                                  listCnt, list, Zrow, out);
  k5a_score<<<dim3(256),  dim3(256), 0, stream>>>(Q, K, qinv, kinv, list, listCnt,
                                                  keyex, wbx);
  k5b_rank<<<dim3(512),   dim3(256), 0, stream>>>(keyex, wbx, listCnt,
                                                  rowcnt, rowk, rowdw);
  k7_fix  <<<dim3(16384), dim3(256), 0, stream>>>(V, rowcnt, rowk, rowdw, Zrow, out);
}

// Round 3
// 475.174 us; speedup vs baseline: 4.9917x; 3.9299x over previous
//
#include <hip/hip_runtime.h>
#include <stdint.h>

typedef unsigned int u32;
typedef unsigned long long u64;
typedef unsigned short u16;
typedef __attribute__((ext_vector_type(8))) short bf16x8;
typedef __attribute__((ext_vector_type(4))) float f32x4;

#define S_ 1024
#define D_ 64
#define NH_ 64
#define BINS_ 16384
#define BSHIFT_ 18
#define TOPK_ 4096u
#define SAMP_ 4u
#define LCAP_ 16384
#define BCAP_ 1024
#define RCAP_ 48
#define CNTSTRIDE_ 32          // pad per-head counters to 128B (XCD false-sharing fix)
#define EPS_ 1e-5f
#define LOGN_ 13.862943611198906f   // log(1024*1024)

__device__ __forceinline__ u32 mono_key(float s){
  u32 u = __float_as_uint(s);
  return (u >> 31) ? ~u : (u | 0x80000000u);   // ascending monotone map
}
__device__ __forceinline__ u16 f2b(float f){
  u32 u = __float_as_uint(f);
  return (u16)((u + 0x7FFFu + ((u >> 16) & 1u)) >> 16);   // f32 -> bf16 RNE
}
__device__ __forceinline__ float b2f(u16 b){
  return __uint_as_float(((u32)b) << 16);
}

// ---------------- K1: inverse norms + normalized bf16 Q,K ----------------
__global__ __launch_bounds__(256) void k1_norm(const float* __restrict__ Q,
    const float* __restrict__ K, float* __restrict__ qinv, float* __restrict__ kinv,
    u16* __restrict__ Qn, u16* __restrict__ Kn){
  int gw = (int)((blockIdx.x * blockDim.x + threadIdx.x) >> 6);
  int d = threadIdx.x & 63;
  if (gw >= 2 * NH_ * S_) return;
  const float* src; float* dst; u16* bdst; int row;
  if (gw < NH_ * S_){ src = Q; dst = qinv; bdst = Qn; row = gw; }
  else               { src = K; dst = kinv; bdst = Kn; row = gw - NH_ * S_; }
  float x = src[(u64)row * D_ + d];
  float ss = x * x;
  #pragma unroll
  for (int m = 32; m; m >>= 1) ss += __shfl_xor(ss, m, 64);
  float inv = 1.0f / (sqrtf(ss) + EPS_);
  if (d == 0) dst[row] = inv;
  bdst[(u64)row * D_ + d] = f2b(x * inv);
}

// ---------------- K1b: V -> VT (bf16, [h][d][k]) via LDS transpose ----------------
__global__ __launch_bounds__(256) void k1b_vt(const float* __restrict__ V,
                                             u16* __restrict__ VT){
  __shared__ u16 tr[64 * 65];
  const int t = threadIdx.x;
  const int h = blockIdx.x >> 4, k0 = (blockIdx.x & 15) * 64;
  for (int idx = t; idx < 4096; idx += 256){
    int r = idx >> 6, d = idx & 63;
    tr[d * 65 + r] = f2b(V[((u64)(h * S_ + k0 + r)) * D_ + d]);
  }
  __syncthreads();
  for (int idx = t; idx < 4096; idx += 256){
    int dr = idx >> 6, c = idx & 63;
    VT[((u64)(h * D_ + dr)) * S_ + k0 + c] = tr[dr * 65 + c];
  }
}

// ---------------- K2: sampled histogram via MFMA (2 blocks per head) ----------------
__global__ __launch_bounds__(512) void k2_hist(const u16* __restrict__ Qn,
    const u16* __restrict__ Kn, u32* __restrict__ Hist){
  __shared__ u32 hist[BINS_];                               // 64KB
  __shared__ __attribute__((aligned(16))) u16 kt2[64 * 64]; // 8KB
  const int t = threadIdx.x, h = blockIdx.x >> 1, qh = blockIdx.x & 1;
  const int w = t >> 6, l = t & 63, lr = l & 15, lg = l >> 4;
  for (int i = t; i < BINS_; i += 512) hist[i] = 0u;
  for (int st = 0; st < 4; ++st){
    const int k0 = (st * 4 + 1) * 64;   // sampled k-tiles {1,5,9,13}
    __syncthreads();
    { int srow = t >> 3, sslot = t & 7;
      *(uint4*)(kt2 + srow * 64 + ((sslot ^ (srow & 7)) * 8)) =
        *(const uint4*)(Kn + ((u64)(h * S_ + k0 + srow)) * D_ + sslot * 8);
    }
    __syncthreads();
    for (int qc = 0; qc < 4; ++qc){
      const u16* qrow = Qn + ((u64)(h * S_ + qh * 512 + qc * 128 + w * 16 + lr)) * D_;
      bf16x8 qa0 = *(const bf16x8*)(qrow + lg * 8);
      bf16x8 qa1 = *(const bf16x8*)(qrow + lg * 8 + 32);
      #pragma unroll
      for (int j = 0; j < 4; ++j){
        int krow = j * 16 + lr, sw = krow & 7;
        bf16x8 kb0 = *(const bf16x8*)(kt2 + krow * 64 + ((lg ^ sw) * 8));
        bf16x8 kb1 = *(const bf16x8*)(kt2 + krow * 64 + (((lg + 4) ^ sw) * 8));
        f32x4 sa = {0.f, 0.f, 0.f, 0.f};
        sa = __builtin_amdgcn_mfma_f32_16x16x32_bf16(qa0, kb0, sa, 0, 0, 0);
        sa = __builtin_amdgcn_mfma_f32_16x16x32_bf16(qa1, kb1, sa, 0, 0, 0);
        #pragma unroll
        for (int r = 0; r < 4; ++r)
          atomicAdd(&hist[mono_key(sa[r]) >> BSHIFT_], 1u);
      }
    }
  }
  __syncthreads();
  for (int i = t; i < BINS_; i += 512){
    u32 c = hist[i];
    if (c) atomicAdd(&Hist[(u64)h * BINS_ + i], c);
  }
}

// ---------------- K3: suffix scan (sampled counts x SAMP) -> weight table + bstar ----------------
__global__ __launch_bounds__(256) void k3_scan(
    const u32* __restrict__ Hist, u16* __restrict__ Wb, u32* __restrict__ bstar)
{
  __shared__ u32 csum[256];
  const int h = blockIdx.x, t = threadIdx.x;
  const u32* Hh = Hist + (u64)h * BINS_;
  u32 local = 0;
  for (int i = 0; i < 64; ++i) local += Hh[t * 64 + i];
  csum[t] = local;
  __syncthreads();
  for (int off = 1; off < 256; off <<= 1){
    u32 v = (t + off < 256) ? csum[t + off] : 0u;
    __syncthreads();
    csum[t] += v;
    __syncthreads();
  }
  u32 g = csum[t] - local;     // sampled count strictly above this thread's bins
  u32 bmin = 0xFFFFFFFFu;
  for (int i = 63; i >= 0; --i){
    int bin = t * 64 + i;
    u32 c = Hh[bin];
    float wmid = LOGN_ - logf((float)(SAMP_ * g) + 0.5f * ((float)(SAMP_ * c) + 1.0f));
    Wb[(u64)h * BINS_ + bin] = f2b(wmid);
    if (SAMP_ * g < TOPK_) bmin = (u32)bin;
    g += c;
  }
  if (bmin != 0xFFFFFFFFu) atomicMin(&bstar[h], bmin);
}

// ---------------- K4: MFMA QK^T -> bin/gather -> MFMA W@V + Z + top collect (LDS list) ----------------
// grid: 64 heads * 8 q-tiles(128 rows); block 512 (8 waves, 16 q-rows each)
__global__ __launch_bounds__(512) void k4_main(
    const u16* __restrict__ Qn, const u16* __restrict__ Kn, const u16* __restrict__ VT,
    const u16* __restrict__ Wb, const u32* __restrict__ bstar,
    u32* __restrict__ listCount, u64* __restrict__ list,
    float* __restrict__ Zrow, float* __restrict__ out)
{
  __shared__ u16 wbl[BINS_];                                 // 32KB
  __shared__ __attribute__((aligned(16))) u16 kt2[64 * 64];  // 8KB
  __shared__ __attribute__((aligned(16))) u16 vt2[64 * 64];  // 8KB
  __shared__ __attribute__((aligned(16))) u16 wt2[128 * 64]; // 16KB
  __shared__ u64 blist[BCAP_];                               // 8KB
  __shared__ u32 bcnt, gbase;
  const int t = threadIdx.x;
  const int h = blockIdx.x >> 3;
  const int q0 = (blockIdx.x & 7) * 128;
  const int w = t >> 6, l = t & 63, lr = l & 15, lg = l >> 4;

  for (int i = t; i < BINS_; i += 512) wbl[i] = Wb[(u64)h * BINS_ + i];
  if (t == 0) bcnt = 0;
  const u32 bst = bstar[h];

  const u16* qrow = Qn + ((u64)(h * S_ + q0 + w * 16 + lr)) * D_;
  bf16x8 qa0 = *(const bf16x8*)(qrow + lg * 8);
  bf16x8 qa1 = *(const bf16x8*)(qrow + lg * 8 + 32);

  f32x4 acc[4] = {{0,0,0,0},{0,0,0,0},{0,0,0,0},{0,0,0,0}};
  float zacc[4] = {0, 0, 0, 0};
  const int srow = t >> 3, sslot = t & 7;

  // prefetch tile 0 into registers
  uint4 kreg = *(const uint4*)(Kn + ((u64)(h * S_ + srow)) * D_ + sslot * 8);
  uint4 vreg = *(const uint4*)(VT + ((u64)(h * D_ + srow)) * S_ + sslot * 8);

  for (int kt0 = 0; kt0 < 16; ++kt0){
    const int k0 = kt0 * 64;
    __syncthreads();   // prev iter's readers of kt2/vt2 done (covers wbl/bcnt init, 1st iter)
    *(uint4*)(kt2 + srow * 64 + ((sslot ^ (srow & 7)) * 8)) = kreg;
    *(uint4*)(vt2 + srow * 64 + ((sslot ^ (srow & 7)) * 8)) = vreg;
    __syncthreads();   // staged
    if (kt0 < 15){     // issue next tile's loads early; they complete under compute
      const int kn0 = k0 + 64;
      kreg = *(const uint4*)(Kn + ((u64)(h * S_ + kn0 + srow)) * D_ + sslot * 8);
      vreg = *(const uint4*)(VT + ((u64)(h * D_ + srow)) * S_ + kn0 + sslot * 8);
    }

    // QK^T + per-element post
    #pragma unroll
    for (int j = 0; j < 4; ++j){
      int krow = j * 16 + lr, sw = krow & 7;
      bf16x8 kb0 = *(const bf16x8*)(kt2 + krow * 64 + ((lg ^ sw) * 8));
      bf16x8 kb1 = *(const bf16x8*)(kt2 + krow * 64 + (((lg + 4) ^ sw) * 8));
      f32x4 sa = {0.f, 0.f, 0.f, 0.f};
      sa = __builtin_amdgcn_mfma_f32_16x16x32_bf16(qa0, kb0, sa, 0, 0, 0);
      sa = __builtin_amdgcn_mfma_f32_16x16x32_bf16(qa1, kb1, sa, 0, 0, 0);
      #pragma unroll
      for (int r = 0; r < 4; ++r){
        u32 key = mono_key(sa[r]);
        u32 bin = key >> BSHIFT_;
        u16 wbits = wbl[bin];
        zacc[r] += b2f(wbits);
        int rw = 16 * w + lg * 4 + r;            // q-row within block tile
        int col = j * 16 + lr;
        int colp = (((col >> 3) ^ (rw & 7)) << 3) | (col & 7);
        wt2[rw * 64 + colp] = wbits;
        if (bin >= bst){
          u32 pos = ((u32)(q0 + rw) << 10) | (u32)(k0 + col);
          u64 ent = ((u64)wbits << 32) | (u64)pos;
          u32 li = atomicAdd(&bcnt, 1u);         // LDS atomic: block-local
          if (li < BCAP_) blist[li] = ent;
          else {                                  // rare overflow: direct reserve
            u32 gi = atomicAdd(&listCount[h * CNTSTRIDE_], 1u);
            if (gi < LCAP_) list[(u64)h * LCAP_ + gi] = ent;
          }
        }
      }
    }
    __syncthreads();   // wt2 ready

    // W @ V-tile
    int ra = 16 * w + lr, swa = ra & 7;
    bf16x8 wa0 = *(const bf16x8*)(wt2 + ra * 64 + ((lg ^ swa) * 8));
    bf16x8 wa1 = *(const bf16x8*)(wt2 + ra * 64 + (((lg + 4) ^ swa) * 8));
    #pragma unroll
    for (int dt = 0; dt < 4; ++dt){
      int rv = dt * 16 + lr, swv = rv & 7;
      bf16x8 vb0 = *(const bf16x8*)(vt2 + rv * 64 + ((lg ^ swv) * 8));
      bf16x8 vb1 = *(const bf16x8*)(vt2 + rv * 64 + (((lg + 4) ^ swv) * 8));
      acc[dt] = __builtin_amdgcn_mfma_f32_16x16x32_bf16(wa0, vb0, acc[dt], 0, 0, 0);
      acc[dt] = __builtin_amdgcn_mfma_f32_16x16x32_bf16(wa1, vb1, acc[dt], 0, 0, 0);
    }
  }

  // flush the block-local candidate list with ONE global atomic
  __syncthreads();
  u32 cnt = bcnt; if (cnt > BCAP_) cnt = BCAP_;
  if (t == 0) gbase = atomicAdd(&listCount[h * CNTSTRIDE_], cnt);
  __syncthreads();
  for (u32 i = t; i < cnt; i += 512){
    u32 gi = gbase + i;
    if (gi < LCAP_) list[(u64)h * LCAP_ + gi] = blist[i];
  }

  // write out (pre-normalization)
  #pragma unroll
  for (int r = 0; r < 4; ++r){
    int q = q0 + 16 * w + lg * 4 + r;
    #pragma unroll
    for (int dt = 0; dt < 4; ++dt)
      out[((u64)(h * S_ + q)) * D_ + dt * 16 + lr] = acc[dt][r];
  }
  // reduce z over the 16 lanes holding one row
  #pragma unroll
  for (int m = 1; m < 16; m <<= 1){
    #pragma unroll
    for (int r = 0; r < 4; ++r) zacc[r] += __shfl_xor(zacc[r], m, 64);
  }
  if (lr == 0){
    #pragma unroll
    for (int r = 0; r < 4; ++r)
      Zrow[h * S_ + q0 + 16 * w + lg * 4 + r] = zacc[r];
  }
}

// ---------------- K5a: exact f32 rescoring of the top list ----------------
__global__ __launch_bounds__(256) void k5a_score(
    const float* __restrict__ Q, const float* __restrict__ K,
    const float* __restrict__ qinv, const float* __restrict__ kinv,
    const u64* __restrict__ list, const u32* __restrict__ listCount,
    u64* __restrict__ keyex, u16* __restrict__ wbx)
{
  const int h = blockIdx.x >> 2, sub = blockIdx.x & 3, t = threadIdx.x;
  u32 T = listCount[h * CNTSTRIDE_]; if (T > LCAP_) T = LCAP_;
  for (u32 e = (u32)(sub * 256 + t); e < T; e += 1024u){
    u64 ent = list[(u64)h * LCAP_ + e];
    u32 wbits = (u32)(ent >> 32);
    u32 pos = (u32)ent;
    u32 q = pos >> 10, k = pos & 1023u;
    const float4* qp = (const float4*)(Q + ((u64)(h * S_ + q)) * D_);
    const float4* kp = (const float4*)(K + ((u64)(h * S_ + k)) * D_);
    float s = 0.f;
    #pragma unroll
    for (int i = 0; i < 16; ++i){
      float4 a = qp[i], b = kp[i];
      s += a.x * b.x + a.y * b.y + a.z * b.z + a.w * b.w;
    }
    s *= qinv[h * S_ + q] * kinv[h * S_ + k];
    keyex[(u64)h * LCAP_ + e] = ((u64)mono_key(s) << 32) | (u64)(0xFFFFFFFFu - pos);
    wbx[(u64)h * LCAP_ + e] = (u16)wbits;
  }
}

// ---------------- K5b: exact pairwise ranks over list -> per-row corrections ----------------
template<int NC>
__device__ __forceinline__ void k5b_scan(const u64* __restrict__ lh, u32 T,
    u64* codes, const u64* mc, u32* rr, int t)
{
  for (u32 c0 = 0; c0 < T; c0 += 8192u){
    u32 cn = T - c0; if (cn > 8192u) cn = 8192u;
    __syncthreads();
    for (u32 i = (u32)t; i < cn; i += 256) codes[i] = lh[c0 + i];
    __syncthreads();
    for (u32 j = 0; j < cn; ++j){
      u64 cj = codes[j];
      #pragma unroll
      for (int i = 0; i < NC; ++i) rr[i] += (cj > mc[i]) ? 1u : 0u;
    }
  }
}

__global__ __launch_bounds__(256) void k5b_rank(
    const u64* __restrict__ keyex, const u16* __restrict__ wbx,
    const u32* __restrict__ listCount,
    u32* __restrict__ rowcnt, u32* __restrict__ rowk, float* __restrict__ rowdw)
{
  __shared__ u64 codes[8192];     // 64KB
  const int h = blockIdx.x >> 3, sl = blockIdx.x & 7, t = threadIdx.x;
  u32 T = listCount[h * CNTSTRIDE_]; if (T > LCAP_) T = LCAP_;
  const u64* lh = keyex + (u64)h * LCAP_;
  u32 e0 = (T * (u32)sl) / 8u, e1 = (T * (u32)(sl + 1)) / 8u;

  u64 mc[8]; u32 rr[8]; u16 wb[8]; bool val[8];
  #pragma unroll
  for (int i = 0; i < 8; ++i){
    u32 e = e0 + (u32)t + (u32)i * 256u;
    val[i] = (e < e1);
    mc[i] = val[i] ? lh[e] : 0xFFFFFFFFFFFFFFFFull;
    wb[i] = val[i] ? wbx[(u64)h * LCAP_ + e] : (u16)0;
    rr[i] = 0;
  }
  u32 ncand = (e1 - e0 + 255u) >> 8;   // block-uniform
  if (ncand <= 2)      k5b_scan<2>(lh, T, codes, mc, rr, t);
  else if (ncand <= 4) k5b_scan<4>(lh, T, codes, mc, rr, t);
  else                 k5b_scan<8>(lh, T, codes, mc, rr, t);

  #pragma unroll
  for (int i = 0; i < 8; ++i){
    if (!val[i]) continue;
    float wex = LOGN_ - logf((float)(rr[i] + 1u));
    float dw = wex - b2f(wb[i]);
    u32 pos = 0xFFFFFFFFu - (u32)(mc[i] & 0xFFFFFFFFull);
    u32 q = pos >> 10, k = pos & 1023u;
    u32 idx = atomicAdd(&rowcnt[h * S_ + q], 1u);
    if (idx < RCAP_){
      rowk [((u64)(h * S_ + q)) * RCAP_ + idx] = k;
      rowdw[((u64)(h * S_ + q)) * RCAP_ + idx] = dw;
    }
  }
}

// ---------------- K7: apply corrections + normalize rows ----------------
__global__ __launch_bounds__(256) void k7_fix(
    const float* __restrict__ V, const u32* __restrict__ rowcnt,
    const u32* __restrict__ rowk, const float* __restrict__ rowdw,
    const float* __restrict__ Zrow, float* __restrict__ out)
{
  int gw = (int)((blockIdx.x * blockDim.x + threadIdx.x) >> 6);
  int lane = threadIdx.x & 63;
  if (gw >= NH_ * S_) return;
  int h = gw >> 10;
  float v = out[(u64)gw * D_ + lane];
  float z = Zrow[gw];
  u32 c = rowcnt[gw]; if (c > RCAP_) c = RCAP_;
  const float* Vh = V + (u64)h * S_ * D_;
  for (u32 j = 0; j < c; ++j){
    u32 k  = rowk [(u64)gw * RCAP_ + j];
    float dw = rowdw[(u64)gw * RCAP_ + j];
    v = fmaf(dw, Vh[(u64)k * D_ + lane], v);
    z += dw;
  }
  out[(u64)gw * D_ + lane] = v / z;
}

extern "C" void kernel_launch(void* const* d_in, const int* in_sizes, int n_in,
                              void* d_out, int out_size, void* d_ws, size_t ws_size,
                              hipStream_t stream)
{
  (void)in_sizes; (void)n_in; (void)out_size;
  const float* Q = (const float*)d_in[0];
  const float* K = (const float*)d_in[1];
  const float* V = (const float*)d_in[2];
  float* out = (float*)d_out;

  uint8_t* w = (uint8_t*)d_ws;
  size_t off = 0;
  auto alloc = [&](size_t bytes) -> void* {
    void* p = w + off;
    off += (bytes + 255) & ~(size_t)255;
    return p;
  };
  float* qinv   = (float*)alloc((size_t)NH_ * S_ * 4);
  float* kinv   = (float*)alloc((size_t)NH_ * S_ * 4);
  u16*   Qn     = (u16*)  alloc((size_t)NH_ * S_ * D_ * 2);
  u16*   Kn     = (u16*)  alloc((size_t)NH_ * S_ * D_ * 2);
  u16*   VT     = (u16*)  alloc((size_t)NH_ * S_ * D_ * 2);
  u32*   Hist   = (u32*)  alloc((size_t)NH_ * BINS_ * 4);
  u16*   Wb     = (u16*)  alloc((size_t)NH_ * BINS_ * 2);
  u32*   bstar  = (u32*)  alloc((size_t)NH_ * 4);
  u32*   listCnt= (u32*)  alloc((size_t)NH_ * CNTSTRIDE_ * 4);
  u64*   list   = (u64*)  alloc((size_t)NH_ * LCAP_ * 8);
  u64*   keyex  = (u64*)  alloc((size_t)NH_ * LCAP_ * 8);
  u16*   wbx    = (u16*)  alloc((size_t)NH_ * LCAP_ * 2);
  float* Zrow   = (float*)alloc((size_t)NH_ * S_ * 4);
  u32*   rowcnt = (u32*)  alloc((size_t)NH_ * S_ * 4);
  u32*   rowk   = (u32*)  alloc((size_t)NH_ * S_ * RCAP_ * 4);
  float* rowdw  = (float*)alloc((size_t)NH_ * S_ * RCAP_ * 4);
  if (off > ws_size) return;

  hipMemsetAsync(Hist,    0,    (size_t)NH_ * BINS_ * 4,      stream);
  hipMemsetAsync(bstar,   0xFF, (size_t)NH_ * 4,              stream);
  hipMemsetAsync(listCnt, 0,    (size_t)NH_ * CNTSTRIDE_ * 4, stream);
  hipMemsetAsync(rowcnt,  0,    (size_t)NH_ * S_ * 4,         stream);

  k1_norm <<<dim3(32768), dim3(256), 0, stream>>>(Q, K, qinv, kinv, Qn, Kn);
  k1b_vt  <<<dim3(1024),  dim3(256), 0, stream>>>(V, VT);
  k2_hist <<<dim3(128),   dim3(512), 0, stream>>>(Qn, Kn, Hist);
  k3_scan <<<dim3(64),    dim3(256), 0, stream>>>(Hist, Wb, bstar);
  k4_main <<<dim3(512),   dim3(512), 0, stream>>>(Qn, Kn, VT, Wb, bstar,
                                                  listCnt, list, Zrow, out);
  k5a_score<<<dim3(256),  dim3(256), 0, stream>>>(Q, K, qinv, kinv, list, listCnt,
                                                  keyex, wbx);
  k5b_rank<<<dim3(512),   dim3(256), 0, stream>>>(keyex, wbx, listCnt,
                                                  rowcnt, rowk, rowdw);
  k7_fix  <<<dim3(16384), dim3(256), 0, stream>>>(V, rowcnt, rowk, rowdw, Zrow, out);
}

// Round 4
// 436.455 us; speedup vs baseline: 5.4346x; 1.0887x over previous
//
#include <hip/hip_runtime.h>
#include <stdint.h>

typedef unsigned int u32;
typedef unsigned long long u64;
typedef unsigned short u16;
typedef __attribute__((ext_vector_type(8))) short bf16x8;
typedef __attribute__((ext_vector_type(4))) float f32x4;

#define S_ 1024
#define D_ 64
#define NH_ 64
#define BINS_ 16384
#define BSHIFT_ 18
#define TOPK_ 4096u
#define SAMP_ 4u
#define LCAP_ 16384
#define BCAP_ 1024
#define RCAP_ 48
#define CNTSTRIDE_ 32          // pad per-head counters to 128B (XCD false-sharing fix)
#define EPS_ 1e-5f
#define LOGN_ 13.862943611198906f   // log(1024*1024)

__device__ __forceinline__ u32 mono_key(float s){
  u32 u = __float_as_uint(s);
  return (u >> 31) ? ~u : (u | 0x80000000u);   // ascending monotone map
}
__device__ __forceinline__ u16 f2b(float f){
  u32 u = __float_as_uint(f);
  return (u16)((u + 0x7FFFu + ((u >> 16) & 1u)) >> 16);   // f32 -> bf16 RNE
}
__device__ __forceinline__ float b2f(u16 b){
  return __uint_as_float(((u32)b) << 16);
}

// ---------------- K1: inverse norms + normalized bf16 Q,K ----------------
__global__ __launch_bounds__(256) void k1_norm(const float* __restrict__ Q,
    const float* __restrict__ K, float* __restrict__ qinv, float* __restrict__ kinv,
    u16* __restrict__ Qn, u16* __restrict__ Kn){
  int gw = (int)((blockIdx.x * blockDim.x + threadIdx.x) >> 6);
  int d = threadIdx.x & 63;
  if (gw >= 2 * NH_ * S_) return;
  const float* src; float* dst; u16* bdst; int row;
  if (gw < NH_ * S_){ src = Q; dst = qinv; bdst = Qn; row = gw; }
  else               { src = K; dst = kinv; bdst = Kn; row = gw - NH_ * S_; }
  float x = src[(u64)row * D_ + d];
  float ss = x * x;
  #pragma unroll
  for (int m = 32; m; m >>= 1) ss += __shfl_xor(ss, m, 64);
  float inv = 1.0f / (sqrtf(ss) + EPS_);
  if (d == 0) dst[row] = inv;
  bdst[(u64)row * D_ + d] = f2b(x * inv);
}

// ---------------- K1b: V -> VT (bf16, [h][d][k]) via LDS transpose ----------------
__global__ __launch_bounds__(256) void k1b_vt(const float* __restrict__ V,
                                             u16* __restrict__ VT){
  __shared__ u16 tr[64 * 65];
  const int t = threadIdx.x;
  const int h = blockIdx.x >> 4, k0 = (blockIdx.x & 15) * 64;
  for (int idx = t; idx < 4096; idx += 256){
    int r = idx >> 6, d = idx & 63;
    tr[d * 65 + r] = f2b(V[((u64)(h * S_ + k0 + r)) * D_ + d]);
  }
  __syncthreads();
  for (int idx = t; idx < 4096; idx += 256){
    int dr = idx >> 6, c = idx & 63;
    VT[((u64)(h * D_ + dr)) * S_ + k0 + c] = tr[dr * 65 + c];
  }
}

// ---------------- K2: sampled histogram via MFMA (4 blocks per head, 1 k-tile each) ----------------
__global__ __launch_bounds__(512) void k2_hist(const u16* __restrict__ Qn,
    const u16* __restrict__ Kn, u32* __restrict__ Hist){
  __shared__ u32 hist[BINS_];                               // 64KB
  __shared__ __attribute__((aligned(16))) u16 kt2[64 * 64]; // 8KB
  const int t = threadIdx.x, h = blockIdx.x >> 2, st = blockIdx.x & 3;
  const int w = t >> 6, l = t & 63, lr = l & 15, lg = l >> 4;
  for (int i = t; i < BINS_; i += 512) hist[i] = 0u;
  const int k0 = (st * 4 + 1) * 64;   // sampled k-tiles {1,5,9,13}
  __syncthreads();
  { int srow = t >> 3, sslot = t & 7;
    *(uint4*)(kt2 + srow * 64 + ((sslot ^ (srow & 7)) * 8)) =
      *(const uint4*)(Kn + ((u64)(h * S_ + k0 + srow)) * D_ + sslot * 8);
  }
  __syncthreads();
  for (int qc = 0; qc < 8; ++qc){
    const u16* qrow = Qn + ((u64)(h * S_ + qc * 128 + w * 16 + lr)) * D_;
    bf16x8 qa0 = *(const bf16x8*)(qrow + lg * 8);
    bf16x8 qa1 = *(const bf16x8*)(qrow + lg * 8 + 32);
    #pragma unroll
    for (int j = 0; j < 4; ++j){
      int krow = j * 16 + lr, sw = krow & 7;
      bf16x8 kb0 = *(const bf16x8*)(kt2 + krow * 64 + ((lg ^ sw) * 8));
      bf16x8 kb1 = *(const bf16x8*)(kt2 + krow * 64 + (((lg + 4) ^ sw) * 8));
      f32x4 sa = {0.f, 0.f, 0.f, 0.f};
      sa = __builtin_amdgcn_mfma_f32_16x16x32_bf16(qa0, kb0, sa, 0, 0, 0);
      sa = __builtin_amdgcn_mfma_f32_16x16x32_bf16(qa1, kb1, sa, 0, 0, 0);
      #pragma unroll
      for (int r = 0; r < 4; ++r)
        atomicAdd(&hist[mono_key(sa[r]) >> BSHIFT_], 1u);
    }
  }
  __syncthreads();
  for (int i = t; i < BINS_; i += 512){
    u32 c = hist[i];
    if (c) atomicAdd(&Hist[(u64)h * BINS_ + i], c);
  }
}

// ---------------- K3: suffix scan (sampled counts x SAMP) -> weight table + bstar ----------------
__global__ __launch_bounds__(256) void k3_scan(
    const u32* __restrict__ Hist, u16* __restrict__ Wb, u32* __restrict__ bstar)
{
  __shared__ u32 csum[256];
  const int h = blockIdx.x, t = threadIdx.x;
  const u32* Hh = Hist + (u64)h * BINS_;
  u32 local = 0;
  for (int i = 0; i < 64; ++i) local += Hh[t * 64 + i];
  csum[t] = local;
  __syncthreads();
  for (int off = 1; off < 256; off <<= 1){
    u32 v = (t + off < 256) ? csum[t + off] : 0u;
    __syncthreads();
    csum[t] += v;
    __syncthreads();
  }
  u32 g = csum[t] - local;     // sampled count strictly above this thread's bins
  u32 bmin = 0xFFFFFFFFu;
  for (int i = 63; i >= 0; --i){
    int bin = t * 64 + i;
    u32 c = Hh[bin];
    float wmid = LOGN_ - logf((float)(SAMP_ * g) + 0.5f * ((float)(SAMP_ * c) + 1.0f));
    Wb[(u64)h * BINS_ + bin] = f2b(wmid);
    if (SAMP_ * g < TOPK_) bmin = (u32)bin;
    g += c;
  }
  if (bmin != 0xFFFFFFFFu) atomicMin(&bstar[h], bmin);
}

// ---------------- K4: MFMA QK^T -> bin/gather -> MFMA W@V + Z + top collect (LDS list) ----------------
// grid: 64 heads * 8 q-tiles(128 rows); block 512 (8 waves, 16 q-rows each)
__global__ __launch_bounds__(512) void k4_main(
    const u16* __restrict__ Qn, const u16* __restrict__ Kn, const u16* __restrict__ VT,
    const u16* __restrict__ Wb, const u32* __restrict__ bstar,
    u32* __restrict__ listCount, u64* __restrict__ list,
    float* __restrict__ Zrow, float* __restrict__ out)
{
  __shared__ u16 wbl[BINS_];                                 // 32KB
  __shared__ __attribute__((aligned(16))) u16 kt2[64 * 64];  // 8KB
  __shared__ __attribute__((aligned(16))) u16 vt2[64 * 64];  // 8KB
  __shared__ __attribute__((aligned(16))) u16 wt2[128 * 64]; // 16KB
  __shared__ u64 blist[BCAP_];                               // 8KB
  __shared__ u32 bcnt, gbase;
  const int t = threadIdx.x;
  const int h = blockIdx.x >> 3;
  const int q0 = (blockIdx.x & 7) * 128;
  const int w = t >> 6, l = t & 63, lr = l & 15, lg = l >> 4;

  for (int i = t; i < BINS_; i += 512) wbl[i] = Wb[(u64)h * BINS_ + i];
  if (t == 0) bcnt = 0;
  const u32 bst = bstar[h];

  const u16* qrow = Qn + ((u64)(h * S_ + q0 + w * 16 + lr)) * D_;
  bf16x8 qa0 = *(const bf16x8*)(qrow + lg * 8);
  bf16x8 qa1 = *(const bf16x8*)(qrow + lg * 8 + 32);

  f32x4 acc[4] = {{0,0,0,0},{0,0,0,0},{0,0,0,0},{0,0,0,0}};
  float zacc[4] = {0, 0, 0, 0};
  const int srow = t >> 3, sslot = t & 7;

  // prefetch tile 0 into registers
  uint4 kreg = *(const uint4*)(Kn + ((u64)(h * S_ + srow)) * D_ + sslot * 8);
  uint4 vreg = *(const uint4*)(VT + ((u64)(h * D_ + srow)) * S_ + sslot * 8);

  for (int kt0 = 0; kt0 < 16; ++kt0){
    const int k0 = kt0 * 64;
    __syncthreads();   // prev iter's readers of kt2/vt2 done (covers wbl/bcnt init, 1st iter)
    *(uint4*)(kt2 + srow * 64 + ((sslot ^ (srow & 7)) * 8)) = kreg;
    *(uint4*)(vt2 + srow * 64 + ((sslot ^ (srow & 7)) * 8)) = vreg;
    __syncthreads();   // staged
    if (kt0 < 15){     // issue next tile's loads early; they complete under compute
      const int kn0 = k0 + 64;
      kreg = *(const uint4*)(Kn + ((u64)(h * S_ + kn0 + srow)) * D_ + sslot * 8);
      vreg = *(const uint4*)(VT + ((u64)(h * D_ + srow)) * S_ + kn0 + sslot * 8);
    }

    // QK^T + per-element post
    #pragma unroll
    for (int j = 0; j < 4; ++j){
      int krow = j * 16 + lr, sw = krow & 7;
      bf16x8 kb0 = *(const bf16x8*)(kt2 + krow * 64 + ((lg ^ sw) * 8));
      bf16x8 kb1 = *(const bf16x8*)(kt2 + krow * 64 + (((lg + 4) ^ sw) * 8));
      f32x4 sa = {0.f, 0.f, 0.f, 0.f};
      sa = __builtin_amdgcn_mfma_f32_16x16x32_bf16(qa0, kb0, sa, 0, 0, 0);
      sa = __builtin_amdgcn_mfma_f32_16x16x32_bf16(qa1, kb1, sa, 0, 0, 0);
      #pragma unroll
      for (int r = 0; r < 4; ++r){
        u32 key = mono_key(sa[r]);
        u32 bin = key >> BSHIFT_;
        u16 wbits = wbl[bin];
        zacc[r] += b2f(wbits);
        int rw = 16 * w + lg * 4 + r;            // q-row within block tile
        int col = j * 16 + lr;
        int colp = (((col >> 3) ^ (rw & 7)) << 3) | (col & 7);
        wt2[rw * 64 + colp] = wbits;
        if (bin >= bst){
          u32 pos = ((u32)(q0 + rw) << 10) | (u32)(k0 + col);
          u64 ent = ((u64)wbits << 32) | (u64)pos;
          u32 li = atomicAdd(&bcnt, 1u);         // LDS atomic: block-local
          if (li < BCAP_) blist[li] = ent;
          else {                                  // rare overflow: direct reserve
            u32 gi = atomicAdd(&listCount[h * CNTSTRIDE_], 1u);
            if (gi < LCAP_) list[(u64)h * LCAP_ + gi] = ent;
          }
        }
      }
    }
    __syncthreads();   // wt2 ready

    // W @ V-tile
    int ra = 16 * w + lr, swa = ra & 7;
    bf16x8 wa0 = *(const bf16x8*)(wt2 + ra * 64 + ((lg ^ swa) * 8));
    bf16x8 wa1 = *(const bf16x8*)(wt2 + ra * 64 + (((lg + 4) ^ swa) * 8));
    #pragma unroll
    for (int dt = 0; dt < 4; ++dt){
      int rv = dt * 16 + lr, swv = rv & 7;
      bf16x8 vb0 = *(const bf16x8*)(vt2 + rv * 64 + ((lg ^ swv) * 8));
      bf16x8 vb1 = *(const bf16x8*)(vt2 + rv * 64 + (((lg + 4) ^ swv) * 8));
      acc[dt] = __builtin_amdgcn_mfma_f32_16x16x32_bf16(wa0, vb0, acc[dt], 0, 0, 0);
      acc[dt] = __builtin_amdgcn_mfma_f32_16x16x32_bf16(wa1, vb1, acc[dt], 0, 0, 0);
    }
  }

  // flush the block-local candidate list with ONE global atomic
  __syncthreads();
  u32 cnt = bcnt; if (cnt > BCAP_) cnt = BCAP_;
  if (t == 0) gbase = atomicAdd(&listCount[h * CNTSTRIDE_], cnt);
  __syncthreads();
  for (u32 i = t; i < cnt; i += 512){
    u32 gi = gbase + i;
    if (gi < LCAP_) list[(u64)h * LCAP_ + gi] = blist[i];
  }

  // write out (pre-normalization)
  #pragma unroll
  for (int r = 0; r < 4; ++r){
    int q = q0 + 16 * w + lg * 4 + r;
    #pragma unroll
    for (int dt = 0; dt < 4; ++dt)
      out[((u64)(h * S_ + q)) * D_ + dt * 16 + lr] = acc[dt][r];
  }
  // reduce z over the 16 lanes holding one row
  #pragma unroll
  for (int m = 1; m < 16; m <<= 1){
    #pragma unroll
    for (int r = 0; r < 4; ++r) zacc[r] += __shfl_xor(zacc[r], m, 64);
  }
  if (lr == 0){
    #pragma unroll
    for (int r = 0; r < 4; ++r)
      Zrow[h * S_ + q0 + 16 * w + lg * 4 + r] = zacc[r];
  }
}

// ---------------- K5a: exact f32 rescoring of the top list ----------------
__global__ __launch_bounds__(256) void k5a_score(
    const float* __restrict__ Q, const float* __restrict__ K,
    const float* __restrict__ qinv, const float* __restrict__ kinv,
    const u64* __restrict__ list, const u32* __restrict__ listCount,
    u64* __restrict__ keyex, u16* __restrict__ wbx)
{
  const int h = blockIdx.x >> 2, sub = blockIdx.x & 3, t = threadIdx.x;
  u32 T = listCount[h * CNTSTRIDE_]; if (T > LCAP_) T = LCAP_;
  for (u32 e = (u32)(sub * 256 + t); e < T; e += 1024u){
    u64 ent = list[(u64)h * LCAP_ + e];
    u32 wbits = (u32)(ent >> 32);
    u32 pos = (u32)ent;
    u32 q = pos >> 10, k = pos & 1023u;
    const float4* qp = (const float4*)(Q + ((u64)(h * S_ + q)) * D_);
    const float4* kp = (const float4*)(K + ((u64)(h * S_ + k)) * D_);
    float s = 0.f;
    #pragma unroll
    for (int i = 0; i < 16; ++i){
      float4 a = qp[i], b = kp[i];
      s += a.x * b.x + a.y * b.y + a.z * b.z + a.w * b.w;
    }
    s *= qinv[h * S_ + q] * kinv[h * S_ + k];
    keyex[(u64)h * LCAP_ + e] = ((u64)mono_key(s) << 32) | (u64)(0xFFFFFFFFu - pos);
    wbx[(u64)h * LCAP_ + e] = (u16)wbits;
  }
}

// ---------------- K5b: adaptive fine-histogram ranks -> per-row corrections ----------------
// grid: 64 blocks (1 per head) x 256
__global__ __launch_bounds__(256) void k5b_rank(
    const u64* __restrict__ keyex, const u16* __restrict__ wbx,
    const u32* __restrict__ listCount,
    u32* __restrict__ rowcnt, u32* __restrict__ rowk, float* __restrict__ rowdw)
{
  __shared__ u32 fh[BINS_];      // 64KB fine histogram -> strict-above counts
  __shared__ u32 rcnt[S_];       // 4KB per-row emission counts
  __shared__ u32 psum[256];
  __shared__ u32 topidx[256];
  __shared__ u32 kmm[2];
  __shared__ u32 topcnt;
  const int h = blockIdx.x, t = threadIdx.x;
  u32 T = listCount[h * CNTSTRIDE_]; if (T > LCAP_) T = LCAP_;
  const u64* lh = keyex + (u64)h * LCAP_;

  for (int i = t; i < BINS_; i += 256) fh[i] = 0u;
  for (int i = t; i < S_; i += 256) rcnt[i] = 0u;
  if (t == 0){ kmm[0] = 0xFFFFFFFFu; kmm[1] = 0u; topcnt = 0u; }
  __syncthreads();

  // pass 0: key min/max
  u32 kmn = 0xFFFFFFFFu, kmx = 0u;
  for (u32 e = (u32)t; e < T; e += 256u){
    u32 k = (u32)(lh[e] >> 32);
    kmn = kmn < k ? kmn : k;
    kmx = kmx > k ? kmx : k;
  }
  #pragma unroll
  for (int m = 1; m < 64; m <<= 1){
    u32 a = __shfl_xor(kmn, m, 64); kmn = kmn < a ? kmn : a;
    u32 b = __shfl_xor(kmx, m, 64); kmx = kmx > b ? kmx : b;
  }
  if ((t & 63) == 0){ atomicMin(&kmm[0], kmn); atomicMax(&kmm[1], kmx); }
  __syncthreads();
  const u32 base = kmm[0];
  const u32 range = kmm[1] - base;
  int sh = 0;
  while ((range >> sh) >= (u32)BINS_) ++sh;

  // pass 1: fine histogram
  for (u32 e = (u32)t; e < T; e += 256u){
    u32 k = (u32)(lh[e] >> 32);
    atomicAdd(&fh[(k - base) >> sh], 1u);
  }
  __syncthreads();

  // suffix scan: fh[b] := count of elements in bins strictly greater than b
  u32 local = 0;
  for (int i = 0; i < 64; ++i) local += fh[t * 64 + i];
  psum[t] = local;
  __syncthreads();
  for (int off = 1; off < 256; off <<= 1){
    u32 v = (t + off < 256) ? psum[t + off] : 0u;
    __syncthreads();
    psum[t] += v;
    __syncthreads();
  }
  u32 g = psum[t] - local;
  for (int i = 63; i >= 0; --i){
    int b = t * 64 + i;
    u32 c = fh[b];
    fh[b] = g;
    g += c;
  }
  __syncthreads();

  // pass 2: midpoint ranks for the bulk; collect top (g<64) for exact pass
  for (u32 e = (u32)t; e < T; e += 256u){
    u64 ent = lh[e];
    u32 k = (u32)(ent >> 32);
    u32 fb = (k - base) >> sh;
    u32 gs = fh[fb];                     // strictly above by bin
    u32 ge = (fb == 0u) ? T : fh[fb - 1];  // above-or-equal bin total
    if (gs < 64u){
      u32 ti = atomicAdd(&topcnt, 1u);
      if (ti < 256u){ topidx[ti] = e; continue; }
    }
    float c = (float)(ge - gs);
    float wex = LOGN_ - logf((float)gs + 0.5f * (c + 1.0f));
    float dw = wex - b2f(wbx[(u64)h * LCAP_ + e]);
    u32 pos = 0xFFFFFFFFu - (u32)ent;
    u32 q = pos >> 10, kk = pos & 1023u;
    u32 idx = atomicAdd(&rcnt[q], 1u);
    if (idx < RCAP_){
      rowk [((u64)(h * S_ + q)) * RCAP_ + idx] = kk;
      rowdw[((u64)(h * S_ + q)) * RCAP_ + idx] = dw;
    }
  }
  __syncthreads();

  // exact pass for the top ~64+ elements: full-list scan each
  u32 tc = topcnt; if (tc > 256u) tc = 256u;
  if ((u32)t < tc){
    u32 e = topidx[t];
    u64 me = lh[e];
    u32 rr = 0;
    u32 j = 0;
    for (; j + 8 <= T; j += 8){
      #pragma unroll
      for (int u = 0; u < 8; ++u) rr += (lh[j + u] > me) ? 1u : 0u;
    }
    for (; j < T; ++j) rr += (lh[j] > me) ? 1u : 0u;
    float wex = LOGN_ - logf((float)(rr + 1u));
    float dw = wex - b2f(wbx[(u64)h * LCAP_ + e]);
    u32 pos = 0xFFFFFFFFu - (u32)me;
    u32 q = pos >> 10, kk = pos & 1023u;
    u32 idx = atomicAdd(&rcnt[q], 1u);
    if (idx < RCAP_){
      rowk [((u64)(h * S_ + q)) * RCAP_ + idx] = kk;
      rowdw[((u64)(h * S_ + q)) * RCAP_ + idx] = dw;
    }
  }
  __syncthreads();
  for (int i = t; i < S_; i += 256) rowcnt[h * S_ + i] = rcnt[i];
}

// ---------------- K7: apply corrections + normalize rows ----------------
__global__ __launch_bounds__(256) void k7_fix(
    const float* __restrict__ V, const u32* __restrict__ rowcnt,
    const u32* __restrict__ rowk, const float* __restrict__ rowdw,
    const float* __restrict__ Zrow, float* __restrict__ out)
{
  int gw = (int)((blockIdx.x * blockDim.x + threadIdx.x) >> 6);
  int lane = threadIdx.x & 63;
  if (gw >= NH_ * S_) return;
  int h = gw >> 10;
  float v = out[(u64)gw * D_ + lane];
  float z = Zrow[gw];
  u32 c = rowcnt[gw]; if (c > RCAP_) c = RCAP_;
  const float* Vh = V + (u64)h * S_ * D_;
  for (u32 j = 0; j < c; ++j){
    u32 k  = rowk [(u64)gw * RCAP_ + j];
    float dw = rowdw[(u64)gw * RCAP_ + j];
    v = fmaf(dw, Vh[(u64)k * D_ + lane], v);
    z += dw;
  }
  out[(u64)gw * D_ + lane] = v / z;
}

extern "C" void kernel_launch(void* const* d_in, const int* in_sizes, int n_in,
                              void* d_out, int out_size, void* d_ws, size_t ws_size,
                              hipStream_t stream)
{
  (void)in_sizes; (void)n_in; (void)out_size;
  const float* Q = (const float*)d_in[0];
  const float* K = (const float*)d_in[1];
  const float* V = (const float*)d_in[2];
  float* out = (float*)d_out;

  uint8_t* w = (uint8_t*)d_ws;
  size_t off = 0;
  auto alloc = [&](size_t bytes) -> void* {
    void* p = w + off;
    off += (bytes + 255) & ~(size_t)255;
    return p;
  };
  float* qinv   = (float*)alloc((size_t)NH_ * S_ * 4);
  float* kinv   = (float*)alloc((size_t)NH_ * S_ * 4);
  u16*   Qn     = (u16*)  alloc((size_t)NH_ * S_ * D_ * 2);
  u16*   Kn     = (u16*)  alloc((size_t)NH_ * S_ * D_ * 2);
  u16*   VT     = (u16*)  alloc((size_t)NH_ * S_ * D_ * 2);
  u32*   Hist   = (u32*)  alloc((size_t)NH_ * BINS_ * 4);
  u16*   Wb     = (u16*)  alloc((size_t)NH_ * BINS_ * 2);
  u32*   bstar  = (u32*)  alloc((size_t)NH_ * 4);
  u32*   listCnt= (u32*)  alloc((size_t)NH_ * CNTSTRIDE_ * 4);
  u64*   list   = (u64*)  alloc((size_t)NH_ * LCAP_ * 8);
  u64*   keyex  = (u64*)  alloc((size_t)NH_ * LCAP_ * 8);
  u16*   wbx    = (u16*)  alloc((size_t)NH_ * LCAP_ * 2);
  float* Zrow   = (float*)alloc((size_t)NH_ * S_ * 4);
  u32*   rowcnt = (u32*)  alloc((size_t)NH_ * S_ * 4);
  u32*   rowk   = (u32*)  alloc((size_t)NH_ * S_ * RCAP_ * 4);
  float* rowdw  = (float*)alloc((size_t)NH_ * S_ * RCAP_ * 4);
  if (off > ws_size) return;

  hipMemsetAsync(Hist,    0,    (size_t)NH_ * BINS_ * 4,      stream);
  hipMemsetAsync(bstar,   0xFF, (size_t)NH_ * 4,              stream);
  hipMemsetAsync(listCnt, 0,    (size_t)NH_ * CNTSTRIDE_ * 4, stream);

  k1_norm <<<dim3(32768), dim3(256), 0, stream>>>(Q, K, qinv, kinv, Qn, Kn);
  k1b_vt  <<<dim3(1024),  dim3(256), 0, stream>>>(V, VT);
  k2_hist <<<dim3(256),   dim3(512), 0, stream>>>(Qn, Kn, Hist);
  k3_scan <<<dim3(64),    dim3(256), 0, stream>>>(Hist, Wb, bstar);
  k4_main <<<dim3(512),   dim3(512), 0, stream>>>(Qn, Kn, VT, Wb, bstar,
                                                  listCnt, list, Zrow, out);
  k5a_score<<<dim3(256),  dim3(256), 0, stream>>>(Q, K, qinv, kinv, list, listCnt,
                                                  keyex, wbx);
  k5b_rank<<<dim3(64),    dim3(256), 0, stream>>>(keyex, wbx, listCnt,
                                                  rowcnt, rowk, rowdw);
  k7_fix  <<<dim3(16384), dim3(256), 0, stream>>>(V, rowcnt, rowk, rowdw, Zrow, out);
}

// Round 5
// 353.917 us; speedup vs baseline: 6.7020x; 1.2332x over previous
//
#include <hip/hip_runtime.h>
#include <stdint.h>

typedef unsigned int u32;
typedef unsigned long long u64;
typedef unsigned short u16;
typedef __attribute__((ext_vector_type(8))) short bf16x8;
typedef __attribute__((ext_vector_type(4))) float f32x4;

#define S_ 1024
#define D_ 64
#define NH_ 64
#define BINS_ 16384
#define BSHIFT_ 18
#define TOPK_ 4096u
#define SAMP_ 4u
#define LCAP_ 16384
#define BCAP_ 1024
#define RCAP_ 48
#define SMAX_ 8192
#define CNTSTRIDE_ 32          // pad per-head counters to 128B (XCD false-sharing fix)
#define EPS_ 1e-5f
#define LOGN_ 13.862943611198906f   // log(1024*1024)

__device__ __forceinline__ u32 mono_key(float s){
  u32 u = __float_as_uint(s);
  return (u >> 31) ? ~u : (u | 0x80000000u);   // ascending monotone map
}
__device__ __forceinline__ u16 f2b(float f){
  u32 u = __float_as_uint(f);
  return (u16)((u + 0x7FFFu + ((u >> 16) & 1u)) >> 16);   // f32 -> bf16 RNE
}
__device__ __forceinline__ float b2f(u16 b){
  return __uint_as_float(((u32)b) << 16);
}

// ---------------- K1: inverse norms + normalized bf16 Q,K ----------------
__global__ __launch_bounds__(256) void k1_norm(const float* __restrict__ Q,
    const float* __restrict__ K, float* __restrict__ qinv, float* __restrict__ kinv,
    u16* __restrict__ Qn, u16* __restrict__ Kn){
  int gw = (int)((blockIdx.x * blockDim.x + threadIdx.x) >> 6);
  int d = threadIdx.x & 63;
  if (gw >= 2 * NH_ * S_) return;
  const float* src; float* dst; u16* bdst; int row;
  if (gw < NH_ * S_){ src = Q; dst = qinv; bdst = Qn; row = gw; }
  else               { src = K; dst = kinv; bdst = Kn; row = gw - NH_ * S_; }
  float x = src[(u64)row * D_ + d];
  float ss = x * x;
  #pragma unroll
  for (int m = 32; m; m >>= 1) ss += __shfl_xor(ss, m, 64);
  float inv = 1.0f / (sqrtf(ss) + EPS_);
  if (d == 0) dst[row] = inv;
  bdst[(u64)row * D_ + d] = f2b(x * inv);
}

// ---------------- K1b: V -> VT (bf16, [h][d][k]) via LDS transpose ----------------
__global__ __launch_bounds__(256) void k1b_vt(const float* __restrict__ V,
                                             u16* __restrict__ VT){
  __shared__ u16 tr[64 * 65];
  const int t = threadIdx.x;
  const int h = blockIdx.x >> 4, k0 = (blockIdx.x & 15) * 64;
  for (int idx = t; idx < 4096; idx += 256){
    int r = idx >> 6, d = idx & 63;
    tr[d * 65 + r] = f2b(V[((u64)(h * S_ + k0 + r)) * D_ + d]);
  }
  __syncthreads();
  for (int idx = t; idx < 4096; idx += 256){
    int dr = idx >> 6, c = idx & 63;
    VT[((u64)(h * D_ + dr)) * S_ + k0 + c] = tr[dr * 65 + c];
  }
}

// ---------------- K2: sampled histogram via MFMA (4 blocks per head, 1 k-tile each) ----------------
__global__ __launch_bounds__(512) void k2_hist(const u16* __restrict__ Qn,
    const u16* __restrict__ Kn, u32* __restrict__ Hist){
  __shared__ u32 hist[BINS_];                               // 64KB
  __shared__ __attribute__((aligned(16))) u16 kt2[64 * 64]; // 8KB
  const int t = threadIdx.x, h = blockIdx.x >> 2, st = blockIdx.x & 3;
  const int w = t >> 6, l = t & 63, lr = l & 15, lg = l >> 4;
  for (int i = t; i < BINS_; i += 512) hist[i] = 0u;
  const int k0 = (st * 4 + 1) * 64;   // sampled k-tiles {1,5,9,13}
  __syncthreads();
  { int srow = t >> 3, sslot = t & 7;
    *(uint4*)(kt2 + srow * 64 + ((sslot ^ (srow & 7)) * 8)) =
      *(const uint4*)(Kn + ((u64)(h * S_ + k0 + srow)) * D_ + sslot * 8);
  }
  __syncthreads();
  for (int qc = 0; qc < 8; ++qc){
    const u16* qrow = Qn + ((u64)(h * S_ + qc * 128 + w * 16 + lr)) * D_;
    bf16x8 qa0 = *(const bf16x8*)(qrow + lg * 8);
    bf16x8 qa1 = *(const bf16x8*)(qrow + lg * 8 + 32);
    #pragma unroll
    for (int j = 0; j < 4; ++j){
      int krow = j * 16 + lr, sw = krow & 7;
      bf16x8 kb0 = *(const bf16x8*)(kt2 + krow * 64 + ((lg ^ sw) * 8));
      bf16x8 kb1 = *(const bf16x8*)(kt2 + krow * 64 + (((lg + 4) ^ sw) * 8));
      f32x4 sa = {0.f, 0.f, 0.f, 0.f};
      sa = __builtin_amdgcn_mfma_f32_16x16x32_bf16(qa0, kb0, sa, 0, 0, 0);
      sa = __builtin_amdgcn_mfma_f32_16x16x32_bf16(qa1, kb1, sa, 0, 0, 0);
      #pragma unroll
      for (int r = 0; r < 4; ++r)
        atomicAdd(&hist[mono_key(sa[r]) >> BSHIFT_], 1u);
    }
  }
  __syncthreads();
  for (int i = t; i < BINS_; i += 512){
    u32 c = hist[i];
    if (c) atomicAdd(&Hist[(u64)h * BINS_ + i], c);
  }
}

// ---------------- K3: suffix scan (sampled counts x SAMP) -> weight table + bstar ----------------
__global__ __launch_bounds__(256) void k3_scan(
    const u32* __restrict__ Hist, u16* __restrict__ Wb, u32* __restrict__ bstar)
{
  __shared__ u32 csum[256];
  const int h = blockIdx.x, t = threadIdx.x;
  const u32* Hh = Hist + (u64)h * BINS_;
  u32 local = 0;
  for (int i = 0; i < 64; ++i) local += Hh[t * 64 + i];
  csum[t] = local;
  __syncthreads();
  for (int off = 1; off < 256; off <<= 1){
    u32 v = (t + off < 256) ? csum[t + off] : 0u;
    __syncthreads();
    csum[t] += v;
    __syncthreads();
  }
  u32 g = csum[t] - local;     // sampled count strictly above this thread's bins
  u32 bmin = 0xFFFFFFFFu;
  for (int i = 63; i >= 0; --i){
    int bin = t * 64 + i;
    u32 c = Hh[bin];
    float wmid = LOGN_ - logf((float)(SAMP_ * g) + 0.5f * ((float)(SAMP_ * c) + 1.0f));
    Wb[(u64)h * BINS_ + bin] = f2b(wmid);
    if (SAMP_ * g < TOPK_) bmin = (u32)bin;
    g += c;
  }
  if (bmin != 0xFFFFFFFFu) atomicMin(&bstar[h], bmin);
}

// ---------------- K4: MFMA QK^T -> bin/gather -> MFMA W@V + Z + top collect (LDS list) ----------------
// grid: 64 heads * 8 q-tiles(128 rows); block 512 (8 waves, 16 q-rows each)
__global__ __launch_bounds__(512) void k4_main(
    const u16* __restrict__ Qn, const u16* __restrict__ Kn, const u16* __restrict__ VT,
    const u16* __restrict__ Wb, const u32* __restrict__ bstar,
    u32* __restrict__ listCount, u64* __restrict__ list,
    float* __restrict__ Zrow, float* __restrict__ out)
{
  __shared__ u16 wbl[BINS_];                                 // 32KB
  __shared__ __attribute__((aligned(16))) u16 kt2[64 * 64];  // 8KB
  __shared__ __attribute__((aligned(16))) u16 vt2[64 * 64];  // 8KB
  __shared__ __attribute__((aligned(16))) u16 wt2[128 * 64]; // 16KB
  __shared__ u64 blist[BCAP_];                               // 8KB
  __shared__ u32 bcnt, gbase;
  const int t = threadIdx.x;
  const int h = blockIdx.x >> 3;
  const int q0 = (blockIdx.x & 7) * 128;
  const int w = t >> 6, l = t & 63, lr = l & 15, lg = l >> 4;

  for (int i = t; i < BINS_; i += 512) wbl[i] = Wb[(u64)h * BINS_ + i];
  if (t == 0) bcnt = 0;
  const u32 bst = bstar[h];

  const u16* qrow = Qn + ((u64)(h * S_ + q0 + w * 16 + lr)) * D_;
  bf16x8 qa0 = *(const bf16x8*)(qrow + lg * 8);
  bf16x8 qa1 = *(const bf16x8*)(qrow + lg * 8 + 32);

  f32x4 acc[4] = {{0,0,0,0},{0,0,0,0},{0,0,0,0},{0,0,0,0}};
  float zacc[4] = {0, 0, 0, 0};
  const int srow = t >> 3, sslot = t & 7;

  // prefetch tile 0 into registers
  uint4 kreg = *(const uint4*)(Kn + ((u64)(h * S_ + srow)) * D_ + sslot * 8);
  uint4 vreg = *(const uint4*)(VT + ((u64)(h * D_ + srow)) * S_ + sslot * 8);

  for (int kt0 = 0; kt0 < 16; ++kt0){
    const int k0 = kt0 * 64;
    __syncthreads();   // prev iter's readers of kt2/vt2 done (covers wbl/bcnt init, 1st iter)
    *(uint4*)(kt2 + srow * 64 + ((sslot ^ (srow & 7)) * 8)) = kreg;
    *(uint4*)(vt2 + srow * 64 + ((sslot ^ (srow & 7)) * 8)) = vreg;
    __syncthreads();   // staged
    if (kt0 < 15){     // issue next tile's loads early; they complete under compute
      const int kn0 = k0 + 64;
      kreg = *(const uint4*)(Kn + ((u64)(h * S_ + kn0 + srow)) * D_ + sslot * 8);
      vreg = *(const uint4*)(VT + ((u64)(h * D_ + srow)) * S_ + kn0 + sslot * 8);
    }

    // QK^T + per-element post
    #pragma unroll
    for (int j = 0; j < 4; ++j){
      int krow = j * 16 + lr, sw = krow & 7;
      bf16x8 kb0 = *(const bf16x8*)(kt2 + krow * 64 + ((lg ^ sw) * 8));
      bf16x8 kb1 = *(const bf16x8*)(kt2 + krow * 64 + (((lg + 4) ^ sw) * 8));
      f32x4 sa = {0.f, 0.f, 0.f, 0.f};
      sa = __builtin_amdgcn_mfma_f32_16x16x32_bf16(qa0, kb0, sa, 0, 0, 0);
      sa = __builtin_amdgcn_mfma_f32_16x16x32_bf16(qa1, kb1, sa, 0, 0, 0);
      #pragma unroll
      for (int r = 0; r < 4; ++r){
        u32 key = mono_key(sa[r]);
        u32 bin = key >> BSHIFT_;
        u16 wbits = wbl[bin];
        zacc[r] += b2f(wbits);
        int rw = 16 * w + lg * 4 + r;            // q-row within block tile
        int col = j * 16 + lr;
        int colp = (((col >> 3) ^ (rw & 7)) << 3) | (col & 7);
        wt2[rw * 64 + colp] = wbits;
        if (bin >= bst){
          u32 pos = ((u32)(q0 + rw) << 10) | (u32)(k0 + col);
          u64 ent = ((u64)wbits << 32) | (u64)pos;
          u32 li = atomicAdd(&bcnt, 1u);         // LDS atomic: block-local
          if (li < BCAP_) blist[li] = ent;
          else {                                  // rare overflow: direct reserve
            u32 gi = atomicAdd(&listCount[h * CNTSTRIDE_], 1u);
            if (gi < LCAP_) list[(u64)h * LCAP_ + gi] = ent;
          }
        }
      }
    }
    __syncthreads();   // wt2 ready

    // W @ V-tile
    int ra = 16 * w + lr, swa = ra & 7;
    bf16x8 wa0 = *(const bf16x8*)(wt2 + ra * 64 + ((lg ^ swa) * 8));
    bf16x8 wa1 = *(const bf16x8*)(wt2 + ra * 64 + (((lg + 4) ^ swa) * 8));
    #pragma unroll
    for (int dt = 0; dt < 4; ++dt){
      int rv = dt * 16 + lr, swv = rv & 7;
      bf16x8 vb0 = *(const bf16x8*)(vt2 + rv * 64 + ((lg ^ swv) * 8));
      bf16x8 vb1 = *(const bf16x8*)(vt2 + rv * 64 + (((lg + 4) ^ swv) * 8));
      acc[dt] = __builtin_amdgcn_mfma_f32_16x16x32_bf16(wa0, vb0, acc[dt], 0, 0, 0);
      acc[dt] = __builtin_amdgcn_mfma_f32_16x16x32_bf16(wa1, vb1, acc[dt], 0, 0, 0);
    }
  }

  // flush the block-local candidate list with ONE global atomic
  __syncthreads();
  u32 cnt = bcnt; if (cnt > BCAP_) cnt = BCAP_;
  if (t == 0) gbase = atomicAdd(&listCount[h * CNTSTRIDE_], cnt);
  __syncthreads();
  for (u32 i = t; i < cnt; i += 512){
    u32 gi = gbase + i;
    if (gi < LCAP_) list[(u64)h * LCAP_ + gi] = blist[i];
  }

  // write out (pre-normalization)
  #pragma unroll
  for (int r = 0; r < 4; ++r){
    int q = q0 + 16 * w + lg * 4 + r;
    #pragma unroll
    for (int dt = 0; dt < 4; ++dt)
      out[((u64)(h * S_ + q)) * D_ + dt * 16 + lr] = acc[dt][r];
  }
  // reduce z over the 16 lanes holding one row
  #pragma unroll
  for (int m = 1; m < 16; m <<= 1){
    #pragma unroll
    for (int r = 0; r < 4; ++r) zacc[r] += __shfl_xor(zacc[r], m, 64);
  }
  if (lr == 0){
    #pragma unroll
    for (int r = 0; r < 4; ++r)
      Zrow[h * S_ + q0 + 16 * w + lg * 4 + r] = zacc[r];
  }
}

// ---------------- K5a: exact f32 rescoring of the top list ----------------
__global__ __launch_bounds__(256) void k5a_score(
    const float* __restrict__ Q, const float* __restrict__ K,
    const float* __restrict__ qinv, const float* __restrict__ kinv,
    const u64* __restrict__ list, const u32* __restrict__ listCount,
    u64* __restrict__ keyex, u16* __restrict__ wbx)
{
  const int h = blockIdx.x >> 2, sub = blockIdx.x & 3, t = threadIdx.x;
  u32 T = listCount[h * CNTSTRIDE_]; if (T > LCAP_) T = LCAP_;
  for (u32 e = (u32)(sub * 256 + t); e < T; e += 1024u){
    u64 ent = list[(u64)h * LCAP_ + e];
    u32 wbits = (u32)(ent >> 32);
    u32 pos = (u32)ent;
    u32 q = pos >> 10, k = pos & 1023u;
    const float4* qp = (const float4*)(Q + ((u64)(h * S_ + q)) * D_);
    const float4* kp = (const float4*)(K + ((u64)(h * S_ + k)) * D_);
    float s = 0.f;
    #pragma unroll
    for (int i = 0; i < 16; ++i){
      float4 a = qp[i], b = kp[i];
      s += a.x * b.x + a.y * b.y + a.z * b.z + a.w * b.w;
    }
    s *= qinv[h * S_ + q] * kinv[h * S_ + k];
    keyex[(u64)h * LCAP_ + e] = ((u64)mono_key(s) << 32) | (u64)(0xFFFFFFFFu - pos);
    wbx[(u64)h * LCAP_ + e] = (u16)wbits;
  }
}

// ---------------- K5b: adaptive fine-histogram ranks -> per-row corrections ----------------
// grid: 64 blocks (1 per head) x 1024; LDS-staged keys, wave-parallel exact pass
__global__ __launch_bounds__(1024) void k5b_rank(
    const u64* __restrict__ keyex, const u16* __restrict__ wbx,
    const u32* __restrict__ listCount,
    u32* __restrict__ rowcnt, u32* __restrict__ rowk, float* __restrict__ rowdw)
{
  __shared__ u32 fh[BINS_];      // 64KB fine histogram -> strict-above counts
  __shared__ u64 skeys[SMAX_];   // 64KB staged keys
  __shared__ u32 rcnt[S_];       // 4KB per-row emission counts
  __shared__ u32 psum[1024];     // 4KB
  __shared__ u32 topidx[256];
  __shared__ u32 kmm[2];
  __shared__ u32 topcnt;
  const int h = blockIdx.x, t = threadIdx.x;
  u32 T = listCount[h * CNTSTRIDE_]; if (T > LCAP_) T = LCAP_;
  const u64* lh = keyex + (u64)h * LCAP_;

  for (int i = t; i < BINS_; i += 1024) fh[i] = 0u;
  for (int i = t; i < S_; i += 1024) rcnt[i] = 0u;
  if (t == 0){ kmm[0] = 0xFFFFFFFFu; kmm[1] = 0u; topcnt = 0u; }
  __syncthreads();

  // pass 0: stage keys to LDS + key min/max
  u32 kmn = 0xFFFFFFFFu, kmx = 0u;
  for (u32 e = (u32)t; e < T; e += 1024u){
    u64 ent = lh[e];
    if (e < SMAX_) skeys[e] = ent;
    u32 k = (u32)(ent >> 32);
    kmn = kmn < k ? kmn : k;
    kmx = kmx > k ? kmx : k;
  }
  #pragma unroll
  for (int m = 1; m < 64; m <<= 1){
    u32 a = __shfl_xor(kmn, m, 64); kmn = kmn < a ? kmn : a;
    u32 b = __shfl_xor(kmx, m, 64); kmx = kmx > b ? kmx : b;
  }
  if ((t & 63) == 0){ atomicMin(&kmm[0], kmn); atomicMax(&kmm[1], kmx); }
  __syncthreads();
  const u32 base = kmm[0];
  const u32 range = kmm[1] - base;
  int sh = 0;
  while ((range >> sh) >= (u32)BINS_) ++sh;

  // pass 1: fine histogram (LDS keys)
  for (u32 e = (u32)t; e < T; e += 1024u){
    u32 k = (u32)((e < SMAX_ ? skeys[e] : lh[e]) >> 32);
    atomicAdd(&fh[(k - base) >> sh], 1u);
  }
  __syncthreads();

  // suffix scan: fh[b] := count of elements in bins strictly greater than b
  u32 local = 0;
  for (int i = 0; i < 16; ++i) local += fh[t * 16 + i];
  psum[t] = local;
  __syncthreads();
  for (int off = 1; off < 1024; off <<= 1){
    u32 v = (t + off < 1024) ? psum[t + off] : 0u;
    __syncthreads();
    psum[t] += v;
    __syncthreads();
  }
  u32 g = psum[t] - local;
  for (int i = 15; i >= 0; --i){
    int b = t * 16 + i;
    u32 c = fh[b];
    fh[b] = g;
    g += c;
  }
  __syncthreads();

  // pass 2: midpoint ranks for the bulk; collect top (g<64) for exact pass
  for (u32 e = (u32)t; e < T; e += 1024u){
    u64 ent = (e < SMAX_ ? skeys[e] : lh[e]);
    u32 k = (u32)(ent >> 32);
    u32 fb = (k - base) >> sh;
    u32 gs = fh[fb];                     // strictly above by bin
    u32 ge = (fb == 0u) ? T : fh[fb - 1];  // above-or-equal bin total
    if (gs < 64u){
      u32 ti = atomicAdd(&topcnt, 1u);
      if (ti < 256u){ topidx[ti] = e; continue; }
    }
    float c = (float)(ge - gs);
    float wex = LOGN_ - logf((float)gs + 0.5f * (c + 1.0f));
    float dw = wex - b2f(wbx[(u64)h * LCAP_ + e]);
    u32 pos = 0xFFFFFFFFu - (u32)ent;
    u32 q = pos >> 10, kk = pos & 1023u;
    u32 idx = atomicAdd(&rcnt[q], 1u);
    if (idx < RCAP_){
      rowk [((u64)(h * S_ + q)) * RCAP_ + idx] = kk;
      rowdw[((u64)(h * S_ + q)) * RCAP_ + idx] = dw;
    }
  }
  __syncthreads();

  // exact pass: one WAVE per top element; 64-lane strided scan of LDS keys
  u32 tc = topcnt; if (tc > 256u) tc = 256u;
  const int wv = t >> 6, ln = t & 63;
  for (u32 ti = (u32)wv; ti < tc; ti += 16u){
    u32 e = topidx[ti];
    u64 me = (e < SMAX_ ? skeys[e] : lh[e]);
    u32 rr = 0;
    for (u32 j = (u32)ln; j < T; j += 64u){
      u64 cj = (j < SMAX_ ? skeys[j] : lh[j]);
      rr += (cj > me) ? 1u : 0u;
    }
    #pragma unroll
    for (int m = 1; m < 64; m <<= 1) rr += __shfl_xor(rr, m, 64);
    if (ln == 0){
      float wex = LOGN_ - logf((float)(rr + 1u));
      float dw = wex - b2f(wbx[(u64)h * LCAP_ + e]);
      u32 pos = 0xFFFFFFFFu - (u32)me;
      u32 q = pos >> 10, kk = pos & 1023u;
      u32 idx = atomicAdd(&rcnt[q], 1u);
      if (idx < RCAP_){
        rowk [((u64)(h * S_ + q)) * RCAP_ + idx] = kk;
        rowdw[((u64)(h * S_ + q)) * RCAP_ + idx] = dw;
      }
    }
  }
  __syncthreads();
  for (int i = t; i < S_; i += 1024) rowcnt[h * S_ + i] = rcnt[i];
}

// ---------------- K7: apply corrections + normalize rows ----------------
__global__ __launch_bounds__(256) void k7_fix(
    const float* __restrict__ V, const u32* __restrict__ rowcnt,
    const u32* __restrict__ rowk, const float* __restrict__ rowdw,
    const float* __restrict__ Zrow, float* __restrict__ out)
{
  int gw = (int)((blockIdx.x * blockDim.x + threadIdx.x) >> 6);
  int lane = threadIdx.x & 63;
  if (gw >= NH_ * S_) return;
  int h = gw >> 10;
  float v = out[(u64)gw * D_ + lane];
  float z = Zrow[gw];
  u32 c = rowcnt[gw]; if (c > RCAP_) c = RCAP_;
  const float* Vh = V + (u64)h * S_ * D_;
  for (u32 j = 0; j < c; ++j){
    u32 k  = rowk [(u64)gw * RCAP_ + j];
    float dw = rowdw[(u64)gw * RCAP_ + j];
    v = fmaf(dw, Vh[(u64)k * D_ + lane], v);
    z += dw;
  }
  out[(u64)gw * D_ + lane] = v / z;
}

extern "C" void kernel_launch(void* const* d_in, const int* in_sizes, int n_in,
                              void* d_out, int out_size, void* d_ws, size_t ws_size,
                              hipStream_t stream)
{
  (void)in_sizes; (void)n_in; (void)out_size;
  const float* Q = (const float*)d_in[0];
  const float* K = (const float*)d_in[1];
  const float* V = (const float*)d_in[2];
  float* out = (float*)d_out;

  uint8_t* w = (uint8_t*)d_ws;
  size_t off = 0;
  auto alloc = [&](size_t bytes) -> void* {
    void* p = w + off;
    off += (bytes + 255) & ~(size_t)255;
    return p;
  };
  float* qinv   = (float*)alloc((size_t)NH_ * S_ * 4);
  float* kinv   = (float*)alloc((size_t)NH_ * S_ * 4);
  u16*   Qn     = (u16*)  alloc((size_t)NH_ * S_ * D_ * 2);
  u16*   Kn     = (u16*)  alloc((size_t)NH_ * S_ * D_ * 2);
  u16*   VT     = (u16*)  alloc((size_t)NH_ * S_ * D_ * 2);
  u32*   Hist   = (u32*)  alloc((size_t)NH_ * BINS_ * 4);
  u16*   Wb     = (u16*)  alloc((size_t)NH_ * BINS_ * 2);
  u32*   bstar  = (u32*)  alloc((size_t)NH_ * 4);
  u32*   listCnt= (u32*)  alloc((size_t)NH_ * CNTSTRIDE_ * 4);
  u64*   list   = (u64*)  alloc((size_t)NH_ * LCAP_ * 8);
  u64*   keyex  = (u64*)  alloc((size_t)NH_ * LCAP_ * 8);
  u16*   wbx    = (u16*)  alloc((size_t)NH_ * LCAP_ * 2);
  float* Zrow   = (float*)alloc((size_t)NH_ * S_ * 4);
  u32*   rowcnt = (u32*)  alloc((size_t)NH_ * S_ * 4);
  u32*   rowk   = (u32*)  alloc((size_t)NH_ * S_ * RCAP_ * 4);
  float* rowdw  = (float*)alloc((size_t)NH_ * S_ * RCAP_ * 4);
  if (off > ws_size) return;

  hipMemsetAsync(Hist,    0,    (size_t)NH_ * BINS_ * 4,      stream);
  hipMemsetAsync(bstar,   0xFF, (size_t)NH_ * 4,              stream);
  hipMemsetAsync(listCnt, 0,    (size_t)NH_ * CNTSTRIDE_ * 4, stream);

  k1_norm <<<dim3(32768), dim3(256), 0, stream>>>(Q, K, qinv, kinv, Qn, Kn);
  k1b_vt  <<<dim3(1024),  dim3(256), 0, stream>>>(V, VT);
  k2_hist <<<dim3(256),   dim3(512), 0, stream>>>(Qn, Kn, Hist);
  k3_scan <<<dim3(64),    dim3(256), 0, stream>>>(Hist, Wb, bstar);
  k4_main <<<dim3(512),   dim3(512), 0, stream>>>(Qn, Kn, VT, Wb, bstar,
                                                  listCnt, list, Zrow, out);
  k5a_score<<<dim3(256),  dim3(256), 0, stream>>>(Q, K, qinv, kinv, list, listCnt,
                                                  keyex, wbx);
  k5b_rank<<<dim3(64),    dim3(1024), 0, stream>>>(keyex, wbx, listCnt,
                                                   rowcnt, rowk, rowdw);
  k7_fix  <<<dim3(16384), dim3(256), 0, stream>>>(V, rowcnt, rowk, rowdw, Zrow, out);
}

// Round 6
// 322.170 us; speedup vs baseline: 7.3624x; 1.0985x over previous
//
#include <hip/hip_runtime.h>
#include <stdint.h>

typedef unsigned int u32;
typedef unsigned long long u64;
typedef unsigned short u16;
typedef __attribute__((ext_vector_type(8))) short bf16x8;
typedef __attribute__((ext_vector_type(4))) float f32x4;

#define S_ 1024
#define D_ 64
#define NH_ 64
#define BINS_ 16384
#define BSHIFT_ 18
#define TOPK_ 4096u
#define SAMP_ 4u
#define LCAP_ 16384
#define BCAP_ 1280
#define RCAP_ 48
#define SMAX_ 8192
#define CNTSTRIDE_ 32          // pad per-head counters to 128B (XCD false-sharing fix)
#define EPS_ 1e-5f
#define LOGN_ 13.862943611198906f   // log(1024*1024)

__device__ __forceinline__ u32 mono_key(float s){
  u32 u = __float_as_uint(s);
  return (u >> 31) ? ~u : (u | 0x80000000u);   // ascending monotone map
}
__device__ __forceinline__ u16 f2b(float f){
  u32 u = __float_as_uint(f);
  return (u16)((u + 0x7FFFu + ((u >> 16) & 1u)) >> 16);   // f32 -> bf16 RNE
}
__device__ __forceinline__ float b2f(u16 b){
  return __uint_as_float(((u32)b) << 16);
}

// ---------------- K1: inverse norms + normalized bf16 Q,K ----------------
__global__ __launch_bounds__(256) void k1_norm(const float* __restrict__ Q,
    const float* __restrict__ K, float* __restrict__ qinv, float* __restrict__ kinv,
    u16* __restrict__ Qn, u16* __restrict__ Kn){
  int gw = (int)((blockIdx.x * blockDim.x + threadIdx.x) >> 6);
  int d = threadIdx.x & 63;
  if (gw >= 2 * NH_ * S_) return;
  const float* src; float* dst; u16* bdst; int row;
  if (gw < NH_ * S_){ src = Q; dst = qinv; bdst = Qn; row = gw; }
  else               { src = K; dst = kinv; bdst = Kn; row = gw - NH_ * S_; }
  float x = src[(u64)row * D_ + d];
  float ss = x * x;
  #pragma unroll
  for (int m = 32; m; m >>= 1) ss += __shfl_xor(ss, m, 64);
  float inv = 1.0f / (sqrtf(ss) + EPS_);
  if (d == 0) dst[row] = inv;
  bdst[(u64)row * D_ + d] = f2b(x * inv);
}

// ---------------- K1b: V -> VT (bf16, [h][d][k]) via LDS transpose ----------------
__global__ __launch_bounds__(256) void k1b_vt(const float* __restrict__ V,
                                             u16* __restrict__ VT){
  __shared__ u16 tr[64 * 65];
  const int t = threadIdx.x;
  const int h = blockIdx.x >> 4, k0 = (blockIdx.x & 15) * 64;
  for (int idx = t; idx < 4096; idx += 256){
    int r = idx >> 6, d = idx & 63;
    tr[d * 65 + r] = f2b(V[((u64)(h * S_ + k0 + r)) * D_ + d]);
  }
  __syncthreads();
  for (int idx = t; idx < 4096; idx += 256){
    int dr = idx >> 6, c = idx & 63;
    VT[((u64)(h * D_ + dr)) * S_ + k0 + c] = tr[dr * 65 + c];
  }
}

// ---------------- K2: sampled histogram via MFMA (4 blocks per head, XCD-local) ----------------
__global__ __launch_bounds__(512) void k2_hist(const u16* __restrict__ Qn,
    const u16* __restrict__ Kn, u32* __restrict__ Hist){
  __shared__ u32 hist[BINS_];                               // 64KB
  __shared__ __attribute__((aligned(16))) u16 kt2[64 * 64]; // 8KB
  const int t = threadIdx.x, h = blockIdx.x & 63, st = blockIdx.x >> 6;
  const int w = t >> 6, l = t & 63, lr = l & 15, lg = l >> 4;
  for (int i = t; i < BINS_; i += 512) hist[i] = 0u;
  const int k0 = (st * 4 + 1) * 64;   // sampled k-tiles {1,5,9,13}
  __syncthreads();
  { int srow = t >> 3, sslot = t & 7;
    *(uint4*)(kt2 + srow * 64 + ((sslot ^ (srow & 7)) * 8)) =
      *(const uint4*)(Kn + ((u64)(h * S_ + k0 + srow)) * D_ + sslot * 8);
  }
  __syncthreads();
  for (int qc = 0; qc < 8; ++qc){
    const u16* qrow = Qn + ((u64)(h * S_ + qc * 128 + w * 16 + lr)) * D_;
    bf16x8 qa0 = *(const bf16x8*)(qrow + lg * 8);
    bf16x8 qa1 = *(const bf16x8*)(qrow + lg * 8 + 32);
    #pragma unroll
    for (int j = 0; j < 4; ++j){
      int krow = j * 16 + lr, sw = krow & 7;
      bf16x8 kb0 = *(const bf16x8*)(kt2 + krow * 64 + ((lg ^ sw) * 8));
      bf16x8 kb1 = *(const bf16x8*)(kt2 + krow * 64 + (((lg + 4) ^ sw) * 8));
      f32x4 sa = {0.f, 0.f, 0.f, 0.f};
      sa = __builtin_amdgcn_mfma_f32_16x16x32_bf16(qa0, kb0, sa, 0, 0, 0);
      sa = __builtin_amdgcn_mfma_f32_16x16x32_bf16(qa1, kb1, sa, 0, 0, 0);
      #pragma unroll
      for (int r = 0; r < 4; ++r)
        atomicAdd(&hist[mono_key(sa[r]) >> BSHIFT_], 1u);
    }
  }
  __syncthreads();
  for (int i = t; i < BINS_; i += 512){
    u32 c = hist[i];
    if (c) atomicAdd(&Hist[(u64)h * BINS_ + i], c);
  }
}

// ---------------- K3: suffix scan (sampled counts x SAMP) -> weight table + bstar ----------------
__global__ __launch_bounds__(256) void k3_scan(
    const u32* __restrict__ Hist, u16* __restrict__ Wb, u32* __restrict__ bstar)
{
  __shared__ u32 csum[256];
  const int h = blockIdx.x, t = threadIdx.x;
  const u32* Hh = Hist + (u64)h * BINS_;
  u32 local = 0;
  for (int i = 0; i < 64; ++i) local += Hh[t * 64 + i];
  csum[t] = local;
  __syncthreads();
  for (int off = 1; off < 256; off <<= 1){
    u32 v = (t + off < 256) ? csum[t + off] : 0u;
    __syncthreads();
    csum[t] += v;
    __syncthreads();
  }
  u32 g = csum[t] - local;     // sampled count strictly above this thread's bins
  u32 bmin = 0xFFFFFFFFu;
  for (int i = 63; i >= 0; --i){
    int bin = t * 64 + i;
    u32 c = Hh[bin];
    float wmid = LOGN_ - logf((float)(SAMP_ * g) + 0.5f * ((float)(SAMP_ * c) + 1.0f));
    Wb[(u64)h * BINS_ + bin] = f2b(wmid);
    if (SAMP_ * g < TOPK_) bmin = (u32)bin;
    g += c;
  }
  if (bmin != 0xFFFFFFFFu) atomicMin(&bstar[h], bmin);
}

// ---------------- K4: swapped MFMA QK^T -> bin/gather -> shfl-exchange -> MFMA W@V ----------------
// grid: 512 blocks, h = blk&63 (XCD-local), q0 = (blk>>6)*128; block 512 (8 waves)
__global__ __launch_bounds__(512, 4) void k4_main(
    const u16* __restrict__ Qn, const u16* __restrict__ Kn, const u16* __restrict__ VT,
    const u16* __restrict__ Wb, const u32* __restrict__ bstar,
    u32* __restrict__ listCount, u64* __restrict__ list,
    float* __restrict__ Zrow, float* __restrict__ out)
{
  __shared__ u16 wbl[BINS_];                                 // 32KB
  __shared__ __attribute__((aligned(16))) u16 kt2[64 * 64];  // 8KB
  __shared__ __attribute__((aligned(16))) u16 vt2[64 * 64];  // 8KB
  __shared__ u64 blist[BCAP_];                               // 10KB
  __shared__ u32 bcnt, gbase;
  const int t = threadIdx.x;
  const int h = blockIdx.x & 63;
  const int q0 = (blockIdx.x >> 6) * 128;
  const int w = t >> 6, l = t & 63, lr = l & 15, lg = l >> 4;

  for (int i = t; i < BINS_; i += 512) wbl[i] = Wb[(u64)h * BINS_ + i];
  if (t == 0) bcnt = 0;
  const u32 bst = bstar[h];
  const int qrow_g = q0 + w * 16 + lr;     // this lane's q row (owns it for QK^T output)

  const u16* qrow = Qn + ((u64)(h * S_ + qrow_g)) * D_;
  bf16x8 qa0 = *(const bf16x8*)(qrow + lg * 8);
  bf16x8 qa1 = *(const bf16x8*)(qrow + lg * 8 + 32);

  f32x4 acc[4] = {{0,0,0,0},{0,0,0,0},{0,0,0,0},{0,0,0,0}};
  float zacc = 0.f;
  const int srow = t >> 3, sslot = t & 7;
  const int srcA = lr + ((lg & 1) << 5);   // exchange partners for W A-frag assembly
  const int srcB = srcA + 16;
  const bool jhi = (lg >> 1) != 0;

  // prefetch tile 0 into registers
  uint4 kreg = *(const uint4*)(Kn + ((u64)(h * S_ + srow)) * D_ + sslot * 8);
  uint4 vreg = *(const uint4*)(VT + ((u64)(h * D_ + srow)) * S_ + sslot * 8);

  for (int kt0 = 0; kt0 < 16; ++kt0){
    const int k0 = kt0 * 64;
    __syncthreads();   // prev tile's readers of kt2/vt2 done (covers wbl/bcnt init, 1st iter)
    *(uint4*)(kt2 + srow * 64 + ((sslot ^ (srow & 7)) * 8)) = kreg;
    *(uint4*)(vt2 + srow * 64 + ((sslot ^ (srow & 7)) * 8)) = vreg;
    __syncthreads();   // staged
    if (kt0 < 15){     // issue next tile's loads early; they complete under compute
      const int kn0 = k0 + 64;
      kreg = *(const uint4*)(Kn + ((u64)(h * S_ + kn0 + srow)) * D_ + sslot * 8);
      vreg = *(const uint4*)(VT + ((u64)(h * D_ + srow)) * S_ + kn0 + sslot * 8);
    }

    // QK^T swapped: sa = K_tile16 x Q_16 -> lane (lr,lg) reg r = S[q=qrow_g][k0+j*16+lg*4+r]
    u32 Plo[4], Phi[4];
    #pragma unroll
    for (int j = 0; j < 4; ++j){
      int krow = j * 16 + lr, sw = krow & 7;
      bf16x8 kb0 = *(const bf16x8*)(kt2 + krow * 64 + ((lg ^ sw) * 8));
      bf16x8 kb1 = *(const bf16x8*)(kt2 + krow * 64 + (((lg + 4) ^ sw) * 8));
      f32x4 sa = {0.f, 0.f, 0.f, 0.f};
      sa = __builtin_amdgcn_mfma_f32_16x16x32_bf16(kb0, qa0, sa, 0, 0, 0);
      sa = __builtin_amdgcn_mfma_f32_16x16x32_bf16(kb1, qa1, sa, 0, 0, 0);
      u32 wb4[4];
      #pragma unroll
      for (int r = 0; r < 4; ++r){
        u32 key = mono_key(sa[r]);
        u32 bin = key >> BSHIFT_;
        u32 wbits = (u32)wbl[bin];
        wb4[r] = wbits;
        zacc += b2f((u16)wbits);
        if (bin >= bst){
          u32 pos = ((u32)qrow_g << 10) | (u32)(k0 + j * 16 + lg * 4 + r);
          u64 ent = ((u64)wbits << 32) | (u64)pos;
          u32 li = atomicAdd(&bcnt, 1u);         // LDS atomic: block-local
          if (li < BCAP_) blist[li] = ent;
          else {                                  // rare overflow: direct reserve
            u32 gi = atomicAdd(&listCount[h * CNTSTRIDE_], 1u);
            if (gi < LCAP_) list[(u64)h * LCAP_ + gi] = ent;
          }
        }
      }
      Plo[j] = wb4[0] | (wb4[1] << 16);
      Phi[j] = wb4[2] | (wb4[3] << 16);
    }

    // in-register exchange: build A-frag W[q=lr][k = lg*8..] from partner lanes
    u32 s0 = (u32)__shfl((int)Plo[0], srcA, 64), s1 = (u32)__shfl((int)Phi[0], srcA, 64);
    u32 s2 = (u32)__shfl((int)Plo[1], srcA, 64), s3 = (u32)__shfl((int)Phi[1], srcA, 64);
    u32 s4 = (u32)__shfl((int)Plo[2], srcA, 64), s5 = (u32)__shfl((int)Phi[2], srcA, 64);
    u32 s6 = (u32)__shfl((int)Plo[3], srcA, 64), s7 = (u32)__shfl((int)Phi[3], srcA, 64);
    u32 r0 = (u32)__shfl((int)Plo[0], srcB, 64), r1 = (u32)__shfl((int)Phi[0], srcB, 64);
    u32 r2 = (u32)__shfl((int)Plo[1], srcB, 64), r3 = (u32)__shfl((int)Phi[1], srcB, 64);
    u32 r4 = (u32)__shfl((int)Plo[2], srcB, 64), r5 = (u32)__shfl((int)Phi[2], srcB, 64);
    u32 r6 = (u32)__shfl((int)Plo[3], srcB, 64), r7 = (u32)__shfl((int)Phi[3], srcB, 64);
    union { u32 u[4]; bf16x8 v; } W0, W1;
    W0.u[0] = jhi ? s2 : s0;  W0.u[1] = jhi ? s3 : s1;
    W0.u[2] = jhi ? r2 : r0;  W0.u[3] = jhi ? r3 : r1;
    W1.u[0] = jhi ? s6 : s4;  W1.u[1] = jhi ? s7 : s5;
    W1.u[2] = jhi ? r6 : r4;  W1.u[3] = jhi ? r7 : r5;

    // W @ V-tile
    #pragma unroll
    for (int dt = 0; dt < 4; ++dt){
      int rv = dt * 16 + lr, swv = rv & 7;
      bf16x8 vb0 = *(const bf16x8*)(vt2 + rv * 64 + ((lg ^ swv) * 8));
      bf16x8 vb1 = *(const bf16x8*)(vt2 + rv * 64 + (((lg + 4) ^ swv) * 8));
      acc[dt] = __builtin_amdgcn_mfma_f32_16x16x32_bf16(W0.v, vb0, acc[dt], 0, 0, 0);
      acc[dt] = __builtin_amdgcn_mfma_f32_16x16x32_bf16(W1.v, vb1, acc[dt], 0, 0, 0);
    }
  }

  // flush the block-local candidate list with ONE global atomic
  __syncthreads();
  u32 cnt = bcnt; if (cnt > BCAP_) cnt = BCAP_;
  if (t == 0) gbase = atomicAdd(&listCount[h * CNTSTRIDE_], cnt);
  __syncthreads();
  for (u32 i = t; i < cnt; i += 512){
    u32 gi = gbase + i;
    if (gi < LCAP_) list[(u64)h * LCAP_ + gi] = blist[i];
  }

  // write out (pre-normalization): lane (lr,lg) reg r -> out[q0+16w+lg*4+r][dt*16+lr]
  #pragma unroll
  for (int r = 0; r < 4; ++r){
    int q = q0 + 16 * w + lg * 4 + r;
    #pragma unroll
    for (int dt = 0; dt < 4; ++dt)
      out[((u64)(h * S_ + q)) * D_ + dt * 16 + lr] = acc[dt][r];
  }
  // z: lane holds partial over its 16 k per tile; reduce across lg group
  zacc += __shfl_xor(zacc, 16, 64);
  zacc += __shfl_xor(zacc, 32, 64);
  if (lg == 0) Zrow[h * S_ + qrow_g] = zacc;
}

// ---------------- K5a: exact f32 rescoring of the top list ----------------
__global__ __launch_bounds__(256) void k5a_score(
    const float* __restrict__ Q, const float* __restrict__ K,
    const float* __restrict__ qinv, const float* __restrict__ kinv,
    const u64* __restrict__ list, const u32* __restrict__ listCount,
    u64* __restrict__ keyex, u16* __restrict__ wbx)
{
  const int h = blockIdx.x & 63, sub = blockIdx.x >> 6, t = threadIdx.x;
  u32 T = listCount[h * CNTSTRIDE_]; if (T > LCAP_) T = LCAP_;
  for (u32 e = (u32)(sub * 256 + t); e < T; e += 1024u){
    u64 ent = list[(u64)h * LCAP_ + e];
    u32 wbits = (u32)(ent >> 32);
    u32 pos = (u32)ent;
    u32 q = pos >> 10, k = pos & 1023u;
    const float4* qp = (const float4*)(Q + ((u64)(h * S_ + q)) * D_);
    const float4* kp = (const float4*)(K + ((u64)(h * S_ + k)) * D_);
    float s = 0.f;
    #pragma unroll
    for (int i = 0; i < 16; ++i){
      float4 a = qp[i], b = kp[i];
      s += a.x * b.x + a.y * b.y + a.z * b.z + a.w * b.w;
    }
    s *= qinv[h * S_ + q] * kinv[h * S_ + k];
    keyex[(u64)h * LCAP_ + e] = ((u64)mono_key(s) << 32) | (u64)(0xFFFFFFFFu - pos);
    wbx[(u64)h * LCAP_ + e] = (u16)wbits;
  }
}

// ---------------- K5b: adaptive fine-histogram ranks -> per-row corrections ----------------
// grid: 64 blocks (1 per head) x 1024; LDS-staged keys, wave-parallel exact pass
__global__ __launch_bounds__(1024) void k5b_rank(
    const u64* __restrict__ keyex, const u16* __restrict__ wbx,
    const u32* __restrict__ listCount,
    u32* __restrict__ rowcnt, u32* __restrict__ rowk, float* __restrict__ rowdw)
{
  __shared__ u32 fh[BINS_];      // 64KB fine histogram -> strict-above counts
  __shared__ u64 skeys[SMAX_];   // 64KB staged keys
  __shared__ u32 rcnt[S_];       // 4KB per-row emission counts
  __shared__ u32 psum[1024];     // 4KB
  __shared__ u32 topidx[256];
  __shared__ u32 kmm[2];
  __shared__ u32 topcnt;
  const int h = blockIdx.x, t = threadIdx.x;
  u32 T = listCount[h * CNTSTRIDE_]; if (T > LCAP_) T = LCAP_;
  const u64* lh = keyex + (u64)h * LCAP_;

  for (int i = t; i < BINS_; i += 1024) fh[i] = 0u;
  for (int i = t; i < S_; i += 1024) rcnt[i] = 0u;
  if (t == 0){ kmm[0] = 0xFFFFFFFFu; kmm[1] = 0u; topcnt = 0u; }
  __syncthreads();

  // pass 0: stage keys to LDS + key min/max
  u32 kmn = 0xFFFFFFFFu, kmx = 0u;
  for (u32 e = (u32)t; e < T; e += 1024u){
    u64 ent = lh[e];
    if (e < SMAX_) skeys[e] = ent;
    u32 k = (u32)(ent >> 32);
    kmn = kmn < k ? kmn : k;
    kmx = kmx > k ? kmx : k;
  }
  #pragma unroll
  for (int m = 1; m < 64; m <<= 1){
    u32 a = __shfl_xor(kmn, m, 64); kmn = kmn < a ? kmn : a;
    u32 b = __shfl_xor(kmx, m, 64); kmx = kmx > b ? kmx : b;
  }
  if ((t & 63) == 0){ atomicMin(&kmm[0], kmn); atomicMax(&kmm[1], kmx); }
  __syncthreads();
  const u32 base = kmm[0];
  const u32 range = kmm[1] - base;
  int sh = 0;
  while ((range >> sh) >= (u32)BINS_) ++sh;

  // pass 1: fine histogram (LDS keys)
  for (u32 e = (u32)t; e < T; e += 1024u){
    u32 k = (u32)((e < SMAX_ ? skeys[e] : lh[e]) >> 32);
    atomicAdd(&fh[(k - base) >> sh], 1u);
  }
  __syncthreads();

  // suffix scan: fh[b] := count of elements in bins strictly greater than b
  u32 local = 0;
  for (int i = 0; i < 16; ++i) local += fh[t * 16 + i];
  psum[t] = local;
  __syncthreads();
  for (int off = 1; off < 1024; off <<= 1){
    u32 v = (t + off < 1024) ? psum[t + off] : 0u;
    __syncthreads();
    psum[t] += v;
    __syncthreads();
  }
  u32 g = psum[t] - local;
  for (int i = 15; i >= 0; --i){
    int b = t * 16 + i;
    u32 c = fh[b];
    fh[b] = g;
    g += c;
  }
  __syncthreads();

  // pass 2: midpoint ranks for the bulk; collect top (g<64) for exact pass
  for (u32 e = (u32)t; e < T; e += 1024u){
    u64 ent = (e < SMAX_ ? skeys[e] : lh[e]);
    u32 k = (u32)(ent >> 32);
    u32 fb = (k - base) >> sh;
    u32 gs = fh[fb];                     // strictly above by bin
    u32 ge = (fb == 0u) ? T : fh[fb - 1];  // above-or-equal bin total
    if (gs < 64u){
      u32 ti = atomicAdd(&topcnt, 1u);
      if (ti < 256u){ topidx[ti] = e; continue; }
    }
    float c = (float)(ge - gs);
    float wex = LOGN_ - logf((float)gs + 0.5f * (c + 1.0f));
    float dw = wex - b2f(wbx[(u64)h * LCAP_ + e]);
    u32 pos = 0xFFFFFFFFu - (u32)ent;
    u32 q = pos >> 10, kk = pos & 1023u;
    u32 idx = atomicAdd(&rcnt[q], 1u);
    if (idx < RCAP_){
      rowk [((u64)(h * S_ + q)) * RCAP_ + idx] = kk;
      rowdw[((u64)(h * S_ + q)) * RCAP_ + idx] = dw;
    }
  }
  __syncthreads();

  // exact pass: one WAVE per top element; 64-lane strided scan of LDS keys
  u32 tc = topcnt; if (tc > 256u) tc = 256u;
  const int wv = t >> 6, ln = t & 63;
  for (u32 ti = (u32)wv; ti < tc; ti += 16u){
    u32 e = topidx[ti];
    u64 me = (e < SMAX_ ? skeys[e] : lh[e]);
    u32 rr = 0;
    for (u32 j = (u32)ln; j < T; j += 64u){
      u64 cj = (j < SMAX_ ? skeys[j] : lh[j]);
      rr += (cj > me) ? 1u : 0u;
    }
    #pragma unroll
    for (int m = 1; m < 64; m <<= 1) rr += __shfl_xor(rr, m, 64);
    if (ln == 0){
      float wex = LOGN_ - logf((float)(rr + 1u));
      float dw = wex - b2f(wbx[(u64)h * LCAP_ + e]);
      u32 pos = 0xFFFFFFFFu - (u32)me;
      u32 q = pos >> 10, kk = pos & 1023u;
      u32 idx = atomicAdd(&rcnt[q], 1u);
      if (idx < RCAP_){
        rowk [((u64)(h * S_ + q)) * RCAP_ + idx] = kk;
        rowdw[((u64)(h * S_ + q)) * RCAP_ + idx] = dw;
      }
    }
  }
  __syncthreads();
  for (int i = t; i < S_; i += 1024) rowcnt[h * S_ + i] = rcnt[i];
}

// ---------------- K7: apply corrections + normalize rows ----------------
__global__ __launch_bounds__(256) void k7_fix(
    const float* __restrict__ V, const u32* __restrict__ rowcnt,
    const u32* __restrict__ rowk, const float* __restrict__ rowdw,
    const float* __restrict__ Zrow, float* __restrict__ out)
{
  int gw = (int)((blockIdx.x * blockDim.x + threadIdx.x) >> 6);
  int lane = threadIdx.x & 63;
  if (gw >= NH_ * S_) return;
  int h = gw >> 10;
  float v = out[(u64)gw * D_ + lane];
  float z = Zrow[gw];
  u32 c = rowcnt[gw]; if (c > RCAP_) c = RCAP_;
  const float* Vh = V + (u64)h * S_ * D_;
  for (u32 j = 0; j < c; ++j){
    u32 k  = rowk [(u64)gw * RCAP_ + j];
    float dw = rowdw[(u64)gw * RCAP_ + j];
    v = fmaf(dw, Vh[(u64)k * D_ + lane], v);
    z += dw;
  }
  out[(u64)gw * D_ + lane] = v / z;
}

extern "C" void kernel_launch(void* const* d_in, const int* in_sizes, int n_in,
                              void* d_out, int out_size, void* d_ws, size_t ws_size,
                              hipStream_t stream)
{
  (void)in_sizes; (void)n_in; (void)out_size;
  const float* Q = (const float*)d_in[0];
  const float* K = (const float*)d_in[1];
  const float* V = (const float*)d_in[2];
  float* out = (float*)d_out;

  uint8_t* w = (uint8_t*)d_ws;
  size_t off = 0;
  auto alloc = [&](size_t bytes) -> void* {
    void* p = w + off;
    off += (bytes + 255) & ~(size_t)255;
    return p;
  };
  float* qinv   = (float*)alloc((size_t)NH_ * S_ * 4);
  float* kinv   = (float*)alloc((size_t)NH_ * S_ * 4);
  u16*   Qn     = (u16*)  alloc((size_t)NH_ * S_ * D_ * 2);
  u16*   Kn     = (u16*)  alloc((size_t)NH_ * S_ * D_ * 2);
  u16*   VT     = (u16*)  alloc((size_t)NH_ * S_ * D_ * 2);
  u32*   Hist   = (u32*)  alloc((size_t)NH_ * BINS_ * 4);
  u16*   Wb     = (u16*)  alloc((size_t)NH_ * BINS_ * 2);
  u32*   bstar  = (u32*)  alloc((size_t)NH_ * 4);
  u32*   listCnt= (u32*)  alloc((size_t)NH_ * CNTSTRIDE_ * 4);
  u64*   list   = (u64*)  alloc((size_t)NH_ * LCAP_ * 8);
  u64*   keyex  = (u64*)  alloc((size_t)NH_ * LCAP_ * 8);
  u16*   wbx    = (u16*)  alloc((size_t)NH_ * LCAP_ * 2);
  float* Zrow   = (float*)alloc((size_t)NH_ * S_ * 4);
  u32*   rowcnt = (u32*)  alloc((size_t)NH_ * S_ * 4);
  u32*   rowk   = (u32*)  alloc((size_t)NH_ * S_ * RCAP_ * 4);
  float* rowdw  = (float*)alloc((size_t)NH_ * S_ * RCAP_ * 4);
  if (off > ws_size) return;

  hipMemsetAsync(Hist,    0,    (size_t)NH_ * BINS_ * 4,      stream);
  hipMemsetAsync(bstar,   0xFF, (size_t)NH_ * 4,              stream);
  hipMemsetAsync(listCnt, 0,    (size_t)NH_ * CNTSTRIDE_ * 4, stream);

  k1_norm <<<dim3(32768), dim3(256), 0, stream>>>(Q, K, qinv, kinv, Qn, Kn);
  k1b_vt  <<<dim3(1024),  dim3(256), 0, stream>>>(V, VT);
  k2_hist <<<dim3(256),   dim3(512), 0, stream>>>(Qn, Kn, Hist);
  k3_scan <<<dim3(64),    dim3(256), 0, stream>>>(Hist, Wb, bstar);
  k4_main <<<dim3(512),   dim3(512), 0, stream>>>(Qn, Kn, VT, Wb, bstar,
                                                  listCnt, list, Zrow, out);
  k5a_score<<<dim3(256),  dim3(256), 0, stream>>>(Q, K, qinv, kinv, list, listCnt,
                                                  keyex, wbx);
  k5b_rank<<<dim3(64),    dim3(1024), 0, stream>>>(keyex, wbx, listCnt,
                                                   rowcnt, rowk, rowdw);
  k7_fix  <<<dim3(16384), dim3(256), 0, stream>>>(V, rowcnt, rowk, rowdw, Zrow, out);
}